// Round 7
// baseline (310.770 us; speedup 1.0000x reference)
//
#include <hip/hip_runtime.h>
#include <stdint.h>

#define S_LEN 2048
#define DMODEL 2048
#define NQH 16
#define NKVH 4
#define HDK 128

typedef __bf16 bf16x8 __attribute__((ext_vector_type(8)));
typedef float f32x4 __attribute__((ext_vector_type(4)));
typedef float f32x16 __attribute__((ext_vector_type(16)));

__device__ __forceinline__ void async16(const void* g, void* l) {
  __builtin_amdgcn_global_load_lds((const __attribute__((address_space(1))) void*)g,
                                   (__attribute__((address_space(3))) void*)l,
                                   16, 0, 0);
}

__device__ __forceinline__ f32x4 mfma16(bf16x8 a, bf16x8 b, f32x4 c) {
  return __builtin_amdgcn_mfma_f32_16x16x32_bf16(a, b, c, 0, 0, 0);
}
__device__ __forceinline__ f32x16 mfma32(bf16x8 a, bf16x8 b, f32x16 c) {
  return __builtin_amdgcn_mfma_f32_32x32x16_bf16(a, b, c, 0, 0, 0);
}
__device__ __forceinline__ uint32_t pkbf16(float lo, float hi) {
  uint32_t r;
  asm("v_cvt_pk_bf16_f32 %0, %1, %2" : "=v"(r) : "v"(lo), "v"(hi));
  return r;
}

// ---------------- fused fp32 -> bf16 conversion (all 5 tensors) ----------------
__global__ __launch_bounds__(256) void cvt_all(
    const float* __restrict__ i0, const float* __restrict__ i1,
    const float* __restrict__ i2, const float* __restrict__ i3,
    const float* __restrict__ i4, __bf16* __restrict__ o0,
    __bf16* __restrict__ o1, __bf16* __restrict__ o2, __bf16* __restrict__ o3,
    __bf16* __restrict__ o4) {
  int v = blockIdx.x * 256 + threadIdx.x;  // vec8 index; total 2359296
  const float* in;
  __bf16* out;
  int base;
  if (v < 1048576)      { in = i0; out = o0; base = 0; }
  else if (v < 1572864) { in = i1; out = o1; base = 1048576; }
  else if (v < 1703936) { in = i2; out = o2; base = 1572864; }
  else if (v < 1835008) { in = i3; out = o3; base = 1703936; }
  else                  { in = i4; out = o4; base = 1835008; }
  int i = (v - base) * 8;
  const float4* p = (const float4*)(in + i);
  float4 a = p[0], b = p[1];
  bf16x8 o;
  o[0] = (__bf16)a.x; o[1] = (__bf16)a.y; o[2] = (__bf16)a.z; o[3] = (__bf16)a.w;
  o[4] = (__bf16)b.x; o[5] = (__bf16)b.y; o[6] = (__bf16)b.z; o[7] = (__bf16)b.w;
  *(bf16x8*)(out + i) = o;
}

// ---------------- GEMM: C[m,n] = sum_k A[m,k]*B[n,k], 3-way N-routed ----------------
template <bool F32OUT>
__global__ __launch_bounds__(256) void gemm_bt(const __bf16* __restrict__ A,
                                               const __bf16* __restrict__ B0,
                                               const __bf16* __restrict__ B1,
                                               const __bf16* __restrict__ B2,
                                               void* __restrict__ C0,
                                               void* __restrict__ C1,
                                               void* __restrict__ C2,
                                               int Ntot, int Ns1, int Ns2, int K) {
  int nbn = Ntot >> 7;
  int nwg = gridDim.x;
  int bid = blockIdx.x;
  int bx = (bid & 7) * (nwg >> 3) + (bid >> 3);  // XCD swizzle (nwg % 8 == 0)
  int m0 = (bx / nbn) << 7;
  int n0g = (bx % nbn) << 7;
  const __bf16* B;
  void* C;
  int n0, Nc;
  if (n0g < Ns1)      { B = B0; C = C0; n0 = n0g;       Nc = Ns1; }
  else if (n0g < Ns2) { B = B1; C = C1; n0 = n0g - Ns1; Nc = Ns2 - Ns1; }
  else                { B = B2; C = C2; n0 = n0g - Ns2; Nc = Ntot - Ns2; }

  __shared__ __align__(16) uint8_t As[16384]; // [128][64] bf16, XOR-swizzled
  __shared__ __align__(16) uint8_t Bs[16384];

  int t = threadIdx.x, lane = t & 63, w = t >> 6;
  int wr = w >> 1, wc = w & 1;
  f32x4 acc[4][4] = {};

  for (int k0 = 0; k0 < K; k0 += 64) {
#pragma unroll
    for (int i = 0; i < 4; ++i) {
      int c = (i << 8) + t;
      int row = c >> 3;
      int colb = ((c & 7) << 4) ^ ((row & 7) << 4);
      async16((const uint8_t*)(A + (size_t)(m0 + row) * K + k0) + colb, As + c * 16);
      async16((const uint8_t*)(B + (size_t)(n0 + row) * K + k0) + colb, Bs + c * 16);
    }
    __syncthreads();
#pragma unroll
    for (int ks = 0; ks < 2; ++ks) {
      bf16x8 af[4], bfr[4];
#pragma unroll
      for (int m = 0; m < 4; ++m) {
        int row = wr * 64 + m * 16 + (lane & 15);
        int colb = ((ks << 6) + ((lane >> 4) << 4)) ^ ((row & 7) << 4);
        af[m] = *(const bf16x8*)(As + row * 128 + colb);
      }
#pragma unroll
      for (int n = 0; n < 4; ++n) {
        int row = wc * 64 + n * 16 + (lane & 15);
        int colb = ((ks << 6) + ((lane >> 4) << 4)) ^ ((row & 7) << 4);
        bfr[n] = *(const bf16x8*)(Bs + row * 128 + colb);
      }
      __builtin_amdgcn_s_setprio(1);
#pragma unroll
      for (int m = 0; m < 4; ++m)
#pragma unroll
        for (int n = 0; n < 4; ++n)
          acc[m][n] = mfma16(af[m], bfr[n], acc[m][n]);
      __builtin_amdgcn_s_setprio(0);
    }
    __syncthreads();
  }
#pragma unroll
  for (int m = 0; m < 4; ++m)
#pragma unroll
    for (int n = 0; n < 4; ++n)
#pragma unroll
      for (int j = 0; j < 4; ++j) {
        int mg = m0 + wr * 64 + m * 16 + ((lane >> 4) << 2) + j;
        int ng = n0 + wc * 64 + n * 16 + (lane & 15);
        float v = acc[m][n][j];
        if (F32OUT) ((float*)C)[(size_t)mg * Nc + ng] = v;
        else        ((__bf16*)C)[(size_t)mg * Nc + ng] = (__bf16)v;
      }
}

// ---------------- V transpose: (B*S, 512) -> Vt[(b*4+kvh)*128 + d][s] ----------------
__global__ __launch_bounds__(256) void transpose_v(const __bf16* __restrict__ V,
                                                   __bf16* __restrict__ Vt) {
  int bid = blockIdx.x;
  int dt = bid & 1, st = (bid >> 1) & 31, kvh = (bid >> 6) & 3, b = bid >> 8;
  __shared__ __align__(16) __bf16 tile[64][72];
  int t = threadIdx.x;
#pragma unroll
  for (int i = 0; i < 2; ++i) {
    int c = (i << 8) + t;
    int sr = c >> 3, cb = (c & 7) << 3;
    bf16x8 v = *(const bf16x8*)(V + (size_t)(b * S_LEN + st * 64 + sr) * 512 +
                                kvh * HDK + dt * 64 + cb);
    *(bf16x8*)(&tile[sr][cb]) = v;
  }
  __syncthreads();
#pragma unroll
  for (int i = 0; i < 2; ++i) {
    int c = (i << 8) + t;
    int dr = c >> 3, sb = (c & 7) << 3;
    bf16x8 o;
#pragma unroll
    for (int j = 0; j < 8; ++j) o[j] = tile[sb + j][dr];
    *(bf16x8*)(Vt + (size_t)((b * NKVH + kvh) * HDK + dt * 64 + dr) * S_LEN +
               st * 64 + sb) = o;
  }
}

// ---------------- causal GQA flash attention, 32x32 swapped-QK^T ----------------
// 4 waves x 32 q-rows (QBLK=128), KVBLK=64, in-register softmax (lane owns q=lane&31).
// Single-buffered 32 KB LDS -> 4 blocks/CU; cross-block TLP hides the stage drain.
__global__ __launch_bounds__(256, 4) void attn(const __bf16* __restrict__ Q,
                                               const __bf16* __restrict__ Kx,
                                               const __bf16* __restrict__ Vt,
                                               __bf16* __restrict__ Ctx) {
  int bid0 = blockIdx.x;
  int bid = ((bid0 & 7) << 6) | (bid0 >> 3);  // XCD swizzle: 512 blocks, 64/XCD
  int qt = 15 - (bid & 15);
  int h = (bid >> 4) & 15;
  int b = bid >> 8;
  int kvh = h >> 2;
  int q0 = qt << 7;
  int t = threadIdx.x, lane = t & 63, w = t >> 6;
  int qr = lane & 31;   // own q-row within wave
  int hi = lane >> 5;
  int qwb = q0 + (w << 5);

  __shared__ __align__(16) uint8_t Ks[16384];  // [64 key][128 d] bf16, swizzled
  __shared__ __align__(16) uint8_t Vs[16384];  // [128 d][64 key] bf16, swizzled

  const __bf16* kbase = Kx + (size_t)b * S_LEN * 512 + kvh * HDK;
  const __bf16* vbase = Vt + (size_t)(b * NKVH + kvh) * HDK * S_LEN;

  auto stage = [&](int kt) {
#pragma unroll
    for (int i = 0; i < 4; ++i) {
      int c = (i << 8) + t;
      int krow = c >> 4;
      int kcolb = ((c & 15) << 4) ^ ((krow & 7) << 4);
      async16((const uint8_t*)(kbase + (size_t)((kt << 6) + krow) * 512) + kcolb,
              Ks + c * 16);
      int vrow = c >> 3;
      int vcolb = ((c & 7) << 4) ^ ((vrow & 7) << 4);
      async16((const uint8_t*)(vbase + (size_t)vrow * S_LEN + (kt << 6)) + vcolb,
              Vs + c * 16);
    }
  };

  int NT = (qt << 1) + 2;
  stage(0);

  // Q fragments: lane holds Q[q = qwb+qr][d = dk*16 + hi*8 + j]
  bf16x8 qf[8];
  {
    const __bf16* qrow = Q + (size_t)(b * S_LEN + qwb + qr) * DMODEL + h * HDK + hi * 8;
#pragma unroll
    for (int dk = 0; dk < 8; ++dk) qf[dk] = *(const bf16x8*)(qrow + dk * 16);
  }
  __syncthreads();  // stage(0) drained

  const float NEG = -3.0e38f;
  const float SC = 0.08838834764831845f;  // 1/sqrt(128)
  float m_run = NEG, l_run = 0.f;
  f32x16 acc[4] = {};  // O[q][d], 4 d-tiles of 32

  for (int kt = 0; kt < NT; ++kt) {
    int k0 = kt << 6;
    if (k0 <= qwb + 31) {  // wave-uniform skip of fully-masked tiles
      // S^T = K Q^T : D[key][q], col=q=lane&31, row=(r&3)+8*(r>>2)+4*hi
      f32x16 st0 = {}, st1 = {};
      __builtin_amdgcn_s_setprio(1);
#pragma unroll
      for (int dk = 0; dk < 8; ++dk) {
        int cb = (dk << 5) + (hi << 4);
        int swz = (qr & 7) << 4;
        bf16x8 kf0 = *(const bf16x8*)(Ks + qr * 256 + (cb ^ swz));
        st0 = mfma32(kf0, qf[dk], st0);
        bf16x8 kf1 = *(const bf16x8*)(Ks + (32 + qr) * 256 + (cb ^ swz));
        st1 = mfma32(kf1, qf[dk], st1);
      }
      __builtin_amdgcn_s_setprio(0);

      // causal mask (diagonal-adjacent tiles only)
      if (k0 + 63 > qwb) {
#pragma unroll
        for (int r = 0; r < 16; ++r) {
          int kl = (r & 3) + ((r >> 2) << 3) + (hi << 2);
          st0[r] = (k0 + kl > qwb + qr) ? NEG : st0[r];
          st1[r] = (k0 + 32 + kl > qwb + qr) ? NEG : st1[r];
        }
      }

      // row max: explicit binary tree (depth 5) + one cross-half merge
      float tm[16];
#pragma unroll
      for (int r = 0; r < 16; ++r) tm[r] = fmaxf(st0[r], st1[r]);
#pragma unroll
      for (int s = 8; s > 0; s >>= 1)
#pragma unroll
        for (int r = 0; r < s; ++r) tm[r] = fmaxf(tm[r], tm[r + s]);
      float mx = fmaxf(tm[0], __shfl_xor(tm[0], 32, 64));

      // defer-max: rescale only when max grows by >8/SC in raw score units
      if (__any(mx > m_run + 90.52f)) {
        float mn = fmaxf(m_run, mx);
        float al = __expf((m_run - mn) * SC);
        l_run *= al;
        m_run = mn;
#pragma unroll
        for (int i = 0; i < 16; ++i) {
          float alr = __shfl(al, (i & 3) + ((i >> 2) << 3) + (hi << 2), 64);
          acc[0][i] *= alr; acc[1][i] *= alr; acc[2][i] *= alr; acc[3][i] *= alr;
        }
      }

      float mSC = m_run * SC;
      float p0[16], p1[16];
#pragma unroll
      for (int r = 0; r < 16; ++r) p0[r] = __expf(fmaf(st0[r], SC, -mSC));
#pragma unroll
      for (int r = 0; r < 16; ++r) p1[r] = __expf(fmaf(st1[r], SC, -mSC));
      // row sum: binary tree + one cross-half merge
      float ts[16];
#pragma unroll
      for (int r = 0; r < 16; ++r) ts[r] = p0[r] + p1[r];
#pragma unroll
      for (int s = 8; s > 0; s >>= 1)
#pragma unroll
        for (int r = 0; r < s; ++r) ts[r] += ts[r + s];
      l_run += ts[0] + __shfl_xor(ts[0], 32, 64);

      // pack P to bf16 and redistribute to PV A-frag layout (shfl_xor + select)
      uint32_t wd0[4][2], wd1[4][2];
#pragma unroll
      for (int g = 0; g < 4; ++g) {
        wd0[g][0] = pkbf16(p0[4 * g + 0], p0[4 * g + 1]);
        wd0[g][1] = pkbf16(p0[4 * g + 2], p0[4 * g + 3]);
        wd1[g][0] = pkbf16(p1[4 * g + 0], p1[4 * g + 1]);
        wd1[g][1] = pkbf16(p1[4 * g + 2], p1[4 * g + 3]);
      }
      bf16x8 pa[4];
#define PEXCH(WD, IDX0, IDX1)                                                  \
      {                                                                        \
        uint32_t s0 = hi ? WD[0][0] : WD[1][0];                                \
        uint32_t s1 = hi ? WD[0][1] : WD[1][1];                                \
        uint32_t s2 = hi ? WD[2][0] : WD[3][0];                                \
        uint32_t s3 = hi ? WD[2][1] : WD[3][1];                                \
        uint32_t r0 = (uint32_t)__shfl_xor((int)s0, 32, 64);                   \
        uint32_t r1 = (uint32_t)__shfl_xor((int)s1, 32, 64);                   \
        uint32_t r2 = (uint32_t)__shfl_xor((int)s2, 32, 64);                   \
        uint32_t r3 = (uint32_t)__shfl_xor((int)s3, 32, 64);                   \
        union { bf16x8 v; uint32_t u[4]; } fa, fb;                             \
        fa.u[0] = hi ? r0 : WD[0][0];                                          \
        fa.u[1] = hi ? r1 : WD[0][1];                                          \
        fa.u[2] = hi ? WD[1][0] : r0;                                          \
        fa.u[3] = hi ? WD[1][1] : r1;                                          \
        fb.u[0] = hi ? r2 : WD[2][0];                                          \
        fb.u[1] = hi ? r3 : WD[2][1];                                          \
        fb.u[2] = hi ? WD[3][0] : r2;                                          \
        fb.u[3] = hi ? WD[3][1] : r3;                                          \
        pa[IDX0] = fa.v;                                                       \
        pa[IDX1] = fb.v;                                                       \
      }
      PEXCH(wd0, 0, 1)
      PEXCH(wd1, 2, 3)
#undef PEXCH

      // O += P V : A=pa (P[q][k]), B=V[k][d] from d-major Vt_lds
      __builtin_amdgcn_s_setprio(1);
#pragma unroll
      for (int dt = 0; dt < 4; ++dt) {
        int row = (dt << 5) + qr;
        int swz = (row & 7) << 4;
#pragma unroll
        for (int kc = 0; kc < 4; ++kc) {
          bf16x8 vf = *(const bf16x8*)(Vs + row * 128 + (((kc << 5) + (hi << 4)) ^ swz));
          acc[dt] = mfma32(pa[kc], vf, acc[dt]);
        }
      }
      __builtin_amdgcn_s_setprio(0);
    }
    __syncthreads();                    // all waves done reading Ks/Vs
    if (kt + 1 < NT) stage(kt + 1);     // overwrite single buffer
    __syncthreads();                    // staged data visible (vmcnt drained)
  }

  // epilogue: normalize by per-row l, write out
#pragma unroll
  for (int i = 0; i < 16; ++i) {
    int rm = (i & 3) + ((i >> 2) << 3) + (hi << 2);
    float lr = __shfl(l_run, rm, 64);
    float inv = 1.0f / lr;
    size_t rowoff = (size_t)(b * S_LEN + qwb + rm) * DMODEL + h * HDK + qr;
#pragma unroll
    for (int dt = 0; dt < 4; ++dt)
      Ctx[rowoff + (dt << 5)] = (__bf16)(acc[dt][i] * inv);
  }
}

// ---------------- launch ----------------
extern "C" void kernel_launch(void* const* d_in, const int* in_sizes, int n_in,
                              void* d_out, int out_size, void* d_ws, size_t ws_size,
                              hipStream_t stream) {
  const float* x  = (const float*)d_in[0];
  const float* Wq = (const float*)d_in[1];
  const float* Wk = (const float*)d_in[2];
  const float* Wv = (const float*)d_in[3];
  const float* Wo = (const float*)d_in[4];
  float* out = (float*)d_out;

  const size_t MB = 1024 * 1024;
  uint8_t* ws = (uint8_t*)d_ws;
  __bf16* xb  = (__bf16*)(ws + 0 * MB);   // 16 MB  (4096 x 2048)
  __bf16* Wqb = (__bf16*)(ws + 16 * MB);  //  8 MB  (2048 x 2048)
  __bf16* Wkb = (__bf16*)(ws + 24 * MB);  //  2 MB  (512 x 2048)
  __bf16* Wvb = (__bf16*)(ws + 26 * MB);  //  2 MB
  __bf16* Wob = (__bf16*)(ws + 28 * MB);  //  8 MB
  __bf16* Qb  = (__bf16*)(ws + 36 * MB);  // 16 MB  (4096 x 2048)
  __bf16* Kb  = (__bf16*)(ws + 52 * MB);  //  4 MB  (4096 x 512)
  __bf16* Vb  = (__bf16*)(ws + 56 * MB);  //  4 MB
  __bf16* Vtb = (__bf16*)(ws + 60 * MB);  //  4 MB  (1024 x 2048)
  __bf16* Ctx = (__bf16*)(ws + 64 * MB);  // 16 MB  (4096 x 2048)

  // fused conversion: 18.9M elems / 8 per thread / 256 per block = 9216 blocks
  cvt_all<<<9216, 256, 0, stream>>>(x, Wq, Wk, Wv, Wo, xb, Wqb, Wkb, Wvb, Wob);

  // fused QKV projection: (4096x2048) x [Wq;Wk;Wv]^T, N = 2048+512+512
  gemm_bt<false><<<(4096 / 128) * (3072 / 128), 256, 0, stream>>>(
      xb, Wqb, Wkb, Wvb, (void*)Qb, (void*)Kb, (void*)Vb, 3072, 2048, 2560, 2048);

  transpose_v<<<512, 256, 0, stream>>>(Vb, Vtb);

  attn<<<512, 256, 0, stream>>>(Qb, Kb, Vtb, Ctx);

  // output projection: (4096x2048) x (2048x2048)^T -> fp32
  gemm_bt<true><<<(4096 / 128) * (2048 / 128), 256, 0, stream>>>(
      Ctx, Wob, Wob, Wob, (void*)out, (void*)out, (void*)out, 2048, 2048, 2048, 2048);
}

// Round 8
// 231.745 us; speedup vs baseline: 1.3410x; 1.3410x over previous
//
#include <hip/hip_runtime.h>
#include <stdint.h>

#define S_LEN 2048
#define DMODEL 2048
#define NQH 16
#define NKVH 4
#define HDK 128

typedef __bf16 bf16x8 __attribute__((ext_vector_type(8)));
typedef float f32x4 __attribute__((ext_vector_type(4)));
typedef float f32x16 __attribute__((ext_vector_type(16)));

__device__ __forceinline__ void async16(const void* g, void* l) {
  __builtin_amdgcn_global_load_lds((const __attribute__((address_space(1))) void*)g,
                                   (__attribute__((address_space(3))) void*)l,
                                   16, 0, 0);
}

__device__ __forceinline__ f32x4 mfma16(bf16x8 a, bf16x8 b, f32x4 c) {
  return __builtin_amdgcn_mfma_f32_16x16x32_bf16(a, b, c, 0, 0, 0);
}
__device__ __forceinline__ f32x16 mfma32(bf16x8 a, bf16x8 b, f32x16 c) {
  return __builtin_amdgcn_mfma_f32_32x32x16_bf16(a, b, c, 0, 0, 0);
}
__device__ __forceinline__ uint32_t pkbf16(float lo, float hi) {
  uint32_t r;
  asm("v_cvt_pk_bf16_f32 %0, %1, %2" : "=v"(r) : "v"(lo), "v"(hi));
  return r;
}

// ---------------- fused fp32 -> bf16 conversion (all 5 tensors) ----------------
__global__ __launch_bounds__(256) void cvt_all(
    const float* __restrict__ i0, const float* __restrict__ i1,
    const float* __restrict__ i2, const float* __restrict__ i3,
    const float* __restrict__ i4, __bf16* __restrict__ o0,
    __bf16* __restrict__ o1, __bf16* __restrict__ o2, __bf16* __restrict__ o3,
    __bf16* __restrict__ o4) {
  int v = blockIdx.x * 256 + threadIdx.x;  // vec8 index; total 2359296
  const float* in;
  __bf16* out;
  int base;
  if (v < 1048576)      { in = i0; out = o0; base = 0; }
  else if (v < 1572864) { in = i1; out = o1; base = 1048576; }
  else if (v < 1703936) { in = i2; out = o2; base = 1572864; }
  else if (v < 1835008) { in = i3; out = o3; base = 1703936; }
  else                  { in = i4; out = o4; base = 1835008; }
  int i = (v - base) * 8;
  const float4* p = (const float4*)(in + i);
  float4 a = p[0], b = p[1];
  bf16x8 o;
  o[0] = (__bf16)a.x; o[1] = (__bf16)a.y; o[2] = (__bf16)a.z; o[3] = (__bf16)a.w;
  o[4] = (__bf16)b.x; o[5] = (__bf16)b.y; o[6] = (__bf16)b.z; o[7] = (__bf16)b.w;
  *(bf16x8*)(out + i) = o;
}

// ---------------- GEMM: C[m,n] = sum_k A[m,k]*B[n,k], 3-way N-routed ----------------
template <bool F32OUT>
__global__ __launch_bounds__(256) void gemm_bt(const __bf16* __restrict__ A,
                                               const __bf16* __restrict__ B0,
                                               const __bf16* __restrict__ B1,
                                               const __bf16* __restrict__ B2,
                                               void* __restrict__ C0,
                                               void* __restrict__ C1,
                                               void* __restrict__ C2,
                                               int Ntot, int Ns1, int Ns2, int K) {
  int nbn = Ntot >> 7;
  int nwg = gridDim.x;
  int bid = blockIdx.x;
  int bx = (bid & 7) * (nwg >> 3) + (bid >> 3);  // XCD swizzle (nwg % 8 == 0)
  int m0 = (bx / nbn) << 7;
  int n0g = (bx % nbn) << 7;
  const __bf16* B;
  void* C;
  int n0, Nc;
  if (n0g < Ns1)      { B = B0; C = C0; n0 = n0g;       Nc = Ns1; }
  else if (n0g < Ns2) { B = B1; C = C1; n0 = n0g - Ns1; Nc = Ns2 - Ns1; }
  else                { B = B2; C = C2; n0 = n0g - Ns2; Nc = Ntot - Ns2; }

  __shared__ __align__(16) uint8_t As[16384]; // [128][64] bf16, XOR-swizzled
  __shared__ __align__(16) uint8_t Bs[16384];

  int t = threadIdx.x, lane = t & 63, w = t >> 6;
  int wr = w >> 1, wc = w & 1;
  f32x4 acc[4][4] = {};

  for (int k0 = 0; k0 < K; k0 += 64) {
#pragma unroll
    for (int i = 0; i < 4; ++i) {
      int c = (i << 8) + t;
      int row = c >> 3;
      int colb = ((c & 7) << 4) ^ ((row & 7) << 4);
      async16((const uint8_t*)(A + (size_t)(m0 + row) * K + k0) + colb, As + c * 16);
      async16((const uint8_t*)(B + (size_t)(n0 + row) * K + k0) + colb, Bs + c * 16);
    }
    __syncthreads();
#pragma unroll
    for (int ks = 0; ks < 2; ++ks) {
      bf16x8 af[4], bfr[4];
#pragma unroll
      for (int m = 0; m < 4; ++m) {
        int row = wr * 64 + m * 16 + (lane & 15);
        int colb = ((ks << 6) + ((lane >> 4) << 4)) ^ ((row & 7) << 4);
        af[m] = *(const bf16x8*)(As + row * 128 + colb);
      }
#pragma unroll
      for (int n = 0; n < 4; ++n) {
        int row = wc * 64 + n * 16 + (lane & 15);
        int colb = ((ks << 6) + ((lane >> 4) << 4)) ^ ((row & 7) << 4);
        bfr[n] = *(const bf16x8*)(Bs + row * 128 + colb);
      }
      __builtin_amdgcn_s_setprio(1);
#pragma unroll
      for (int m = 0; m < 4; ++m)
#pragma unroll
        for (int n = 0; n < 4; ++n)
          acc[m][n] = mfma16(af[m], bfr[n], acc[m][n]);
      __builtin_amdgcn_s_setprio(0);
    }
    __syncthreads();
  }
#pragma unroll
  for (int m = 0; m < 4; ++m)
#pragma unroll
    for (int n = 0; n < 4; ++n)
#pragma unroll
      for (int j = 0; j < 4; ++j) {
        int mg = m0 + wr * 64 + m * 16 + ((lane >> 4) << 2) + j;
        int ng = n0 + wc * 64 + n * 16 + (lane & 15);
        float v = acc[m][n][j];
        if (F32OUT) ((float*)C)[(size_t)mg * Nc + ng] = v;
        else        ((__bf16*)C)[(size_t)mg * Nc + ng] = (__bf16)v;
      }
}

// ---------------- V transpose: (B*S, 512) -> Vt[(b*4+kvh)*128 + d][s] ----------------
__global__ __launch_bounds__(256) void transpose_v(const __bf16* __restrict__ V,
                                                   __bf16* __restrict__ Vt) {
  int bid = blockIdx.x;
  int dt = bid & 1, st = (bid >> 1) & 31, kvh = (bid >> 6) & 3, b = bid >> 8;
  __shared__ __align__(16) __bf16 tile[64][72];
  int t = threadIdx.x;
#pragma unroll
  for (int i = 0; i < 2; ++i) {
    int c = (i << 8) + t;
    int sr = c >> 3, cb = (c & 7) << 3;
    bf16x8 v = *(const bf16x8*)(V + (size_t)(b * S_LEN + st * 64 + sr) * 512 +
                                kvh * HDK + dt * 64 + cb);
    *(bf16x8*)(&tile[sr][cb]) = v;
  }
  __syncthreads();
#pragma unroll
  for (int i = 0; i < 2; ++i) {
    int c = (i << 8) + t;
    int dr = c >> 3, sb = (c & 7) << 3;
    bf16x8 o;
#pragma unroll
    for (int j = 0; j < 8; ++j) o[j] = tile[sb + j][dr];
    *(bf16x8*)(Vt + (size_t)((b * NKVH + kvh) * HDK + dt * 64 + dr) * S_LEN +
               st * 64 + sb) = o;
  }
}

// ---------------- causal GQA flash attention, 32x32 swapped-QK^T ----------------
// QBLK=64: 4 waves = 2 q-subtiles (wq) x 2 kv-halves (kh). Grid 1024 blocks.
// K double-buffered in 32KB LDS; V read directly from L2-resident Vt (XCD-pinned).
// kv-halves run independent online softmax; flash-merge via dead K LDS at end.
__global__ __launch_bounds__(256, 3) void attn(const __bf16* __restrict__ Q,
                                               const __bf16* __restrict__ Kx,
                                               const __bf16* __restrict__ Vt,
                                               __bf16* __restrict__ Ctx) {
  int bid0 = blockIdx.x;
  int combo = bid0 & 7;   // = b*4+kvh -> XCD affinity (K+V+Q slice L2-resident)
  int within = bid0 >> 3; // 0..127
  int b = combo >> 2, kvh = combo & 3;
  int h = (kvh << 2) + (within >> 5);
  int qt = 31 - (within & 31);  // longest blocks first
  int q0 = qt << 6;
  int t = threadIdx.x, lane = t & 63, w = t >> 6;
  int wq = w & 1, kh = w >> 1;
  int qr = lane & 31;   // own q-row within wave
  int hi = lane >> 5;
  int qwb = q0 + (wq << 5);
  int kofs = kh << 5;   // this wave's key offset within each 64-key tile

  __shared__ __align__(16) uint8_t Ks[2][16384];  // [64 key][128 d] bf16, swizzled
  __shared__ float MLs[2][2][32];                 // [wq][m/l][qr] from kh=1 waves

  const __bf16* kbase = Kx + (size_t)b * S_LEN * 512 + kvh * HDK;
  const __bf16* vbase = Vt + (size_t)(b * NKVH + kvh) * HDK * S_LEN;

  auto stage = [&](int kt, int bufi) {
#pragma unroll
    for (int i = 0; i < 4; ++i) {
      int c = (i << 8) + t;
      int krow = c >> 4;
      int kcolb = ((c & 15) << 4) ^ ((krow & 7) << 4);
      async16((const uint8_t*)(kbase + (size_t)((kt << 6) + krow) * 512) + kcolb,
              Ks[bufi] + c * 16);
    }
  };

  int NT = qt + 1;
  stage(0, 0);

  // Q fragments: lane holds Q[q = qwb+qr][d = dk*16 + hi*8 + j]
  bf16x8 qf[8];
  {
    const __bf16* qrow = Q + (size_t)(b * S_LEN + qwb + qr) * DMODEL + h * HDK + hi * 8;
#pragma unroll
    for (int dk = 0; dk < 8; ++dk) qf[dk] = *(const bf16x8*)(qrow + dk * 16);
  }
  __syncthreads();  // stage(0) drained

  const float NEG = -3.0e38f;
  const float SC = 0.08838834764831845f;  // 1/sqrt(128)
  float m_run = NEG, l_run = 0.f;
  f32x16 acc[4] = {};  // O[q][d], 4 d-tiles of 32

  for (int kt = 0; kt < NT; ++kt) {
    int cur = kt & 1;
    if (kt + 1 < NT) stage(kt + 1, cur ^ 1);
    int k0 = kt << 6;
    if (k0 + kofs <= qwb + 31) {  // wave-uniform skip of fully-masked half-tiles
      const uint8_t* ks = Ks[cur];

      // S^T = K Q^T : D[key][q], col=q=lane&31, row=(r&3)+8*(r>>2)+4*hi
      f32x16 st = {};
      int swz = (qr & 7) << 4;
      __builtin_amdgcn_s_setprio(1);
#pragma unroll
      for (int dk = 0; dk < 8; ++dk) {
        bf16x8 kf = *(const bf16x8*)(ks + (kofs + qr) * 256 +
                                     (((dk << 5) + (hi << 4)) ^ swz));
        st = mfma32(kf, qf[dk], st);
      }
      __builtin_amdgcn_s_setprio(0);

      // causal mask (diagonal-adjacent half-tiles only)
      if (k0 + kofs + 31 > qwb) {
#pragma unroll
        for (int r = 0; r < 16; ++r) {
          int kl = (r & 3) + ((r >> 2) << 3) + (hi << 2);
          st[r] = (k0 + kofs + kl > qwb + qr) ? NEG : st[r];
        }
      }

      // row max: binary tree (depth 4) + one cross-hi merge
      float tm[8];
#pragma unroll
      for (int r = 0; r < 8; ++r) tm[r] = fmaxf(st[r], st[r + 8]);
#pragma unroll
      for (int s = 4; s > 0; s >>= 1)
#pragma unroll
        for (int r = 0; r < s; ++r) tm[r] = fmaxf(tm[r], tm[r + s]);
      float mx = fmaxf(tm[0], __shfl_xor(tm[0], 32, 64));

      // defer-max: rescale only when max grows by >8/SC in raw score units
      if (__any(mx > m_run + 90.52f)) {
        float mn = fmaxf(m_run, mx);
        float al = __expf((m_run - mn) * SC);
        l_run *= al;
        m_run = mn;
#pragma unroll
        for (int i = 0; i < 16; ++i) {
          float alr = __shfl(al, (i & 3) + ((i >> 2) << 3) + (hi << 2), 64);
          acc[0][i] *= alr; acc[1][i] *= alr; acc[2][i] *= alr; acc[3][i] *= alr;
        }
      }

      float mSC = m_run * SC;
      float p0[16];
#pragma unroll
      for (int r = 0; r < 16; ++r) p0[r] = __expf(fmaf(st[r], SC, -mSC));
      // row sum: binary tree + one cross-hi merge
      float ts[8];
#pragma unroll
      for (int r = 0; r < 8; ++r) ts[r] = p0[r] + p0[r + 8];
#pragma unroll
      for (int s = 4; s > 0; s >>= 1)
#pragma unroll
        for (int r = 0; r < s; ++r) ts[r] += ts[r + s];
      l_run += ts[0] + __shfl_xor(ts[0], 32, 64);

      // pack P to bf16 and redistribute to PV A-frag layout (shfl_xor + select)
      uint32_t wd0[4][2];
#pragma unroll
      for (int g = 0; g < 4; ++g) {
        wd0[g][0] = pkbf16(p0[4 * g + 0], p0[4 * g + 1]);
        wd0[g][1] = pkbf16(p0[4 * g + 2], p0[4 * g + 3]);
      }
      bf16x8 pa[2];
      {
        uint32_t s0 = hi ? wd0[0][0] : wd0[1][0];
        uint32_t s1 = hi ? wd0[0][1] : wd0[1][1];
        uint32_t s2 = hi ? wd0[2][0] : wd0[3][0];
        uint32_t s3 = hi ? wd0[2][1] : wd0[3][1];
        uint32_t r0 = (uint32_t)__shfl_xor((int)s0, 32, 64);
        uint32_t r1 = (uint32_t)__shfl_xor((int)s1, 32, 64);
        uint32_t r2 = (uint32_t)__shfl_xor((int)s2, 32, 64);
        uint32_t r3 = (uint32_t)__shfl_xor((int)s3, 32, 64);
        union { bf16x8 v; uint32_t u[4]; } fa, fb;
        fa.u[0] = hi ? r0 : wd0[0][0];
        fa.u[1] = hi ? r1 : wd0[0][1];
        fa.u[2] = hi ? wd0[1][0] : r0;
        fa.u[3] = hi ? wd0[1][1] : r1;
        fb.u[0] = hi ? r2 : wd0[2][0];
        fb.u[1] = hi ? r3 : wd0[2][1];
        fb.u[2] = hi ? wd0[3][0] : r2;
        fb.u[3] = hi ? wd0[3][1] : r3;
        pa[0] = fa.v;
        pa[1] = fb.v;
      }

      // O += P V : A=pa (P[q][k]), B=V[k][d] read directly from L2-resident Vt
      const __bf16* vrow0 = vbase + k0 + kofs + (hi << 3);
      __builtin_amdgcn_s_setprio(1);
#pragma unroll
      for (int dt = 0; dt < 4; ++dt) {
        int row = (dt << 5) + qr;
#pragma unroll
        for (int kc = 0; kc < 2; ++kc) {
          bf16x8 vf = *(const bf16x8*)(vrow0 + (size_t)row * S_LEN + (kc << 4));
          acc[dt] = mfma32(pa[kc], vf, acc[dt]);
        }
      }
      __builtin_amdgcn_s_setprio(0);
    }
    __syncthreads();  // all waves past reads of Ks[cur]; next-tile stage drained
  }

  // ---- intra-block flash-merge of the two key-halves (K LDS is dead now) ----
  float* obuf = (float*)(&Ks[0][0]) + wq * 4096;  // 16KB per wq
  if (kh) {
    if (hi == 0) { MLs[wq][0][qr] = m_run; MLs[wq][1][qr] = l_run; }
#pragma unroll
    for (int dt = 0; dt < 4; ++dt)
#pragma unroll
      for (int i4 = 0; i4 < 4; ++i4) {
        f32x4 v4 = {acc[dt][i4 * 4 + 0], acc[dt][i4 * 4 + 1],
                    acc[dt][i4 * 4 + 2], acc[dt][i4 * 4 + 3]};
        *(f32x4*)(obuf + dt * 1024 + lane * 16 + i4 * 4) = v4;
      }
  }
  __syncthreads();
  if (!kh) {
    float m1 = MLs[wq][0][qr], l1 = MLs[wq][1][qr];
    float ms = fmaxf(m_run, m1);
    float a0 = __expf((m_run - ms) * SC);
    float a1 = __expf((m1 - ms) * SC);
    float linv = 1.f / (l_run * a0 + l1 * a1);
#pragma unroll
    for (int i = 0; i < 16; ++i) {
      int rm = (i & 3) + ((i >> 2) << 3) + (hi << 2);
      float a0r = __shfl(a0, rm, 64);
      float a1r = __shfl(a1, rm, 64);
      float invr = __shfl(linv, rm, 64);
      size_t rowoff = (size_t)(b * S_LEN + qwb + rm) * DMODEL + h * HDK + qr;
#pragma unroll
      for (int dt = 0; dt < 4; ++dt) {
        float o1 = obuf[dt * 1024 + lane * 16 + i];
        Ctx[rowoff + (dt << 5)] =
            (__bf16)((acc[dt][i] * a0r + o1 * a1r) * invr);
      }
    }
  }
}

// ---------------- launch ----------------
extern "C" void kernel_launch(void* const* d_in, const int* in_sizes, int n_in,
                              void* d_out, int out_size, void* d_ws, size_t ws_size,
                              hipStream_t stream) {
  const float* x  = (const float*)d_in[0];
  const float* Wq = (const float*)d_in[1];
  const float* Wk = (const float*)d_in[2];
  const float* Wv = (const float*)d_in[3];
  const float* Wo = (const float*)d_in[4];
  float* out = (float*)d_out;

  const size_t MB = 1024 * 1024;
  uint8_t* ws = (uint8_t*)d_ws;
  __bf16* xb  = (__bf16*)(ws + 0 * MB);   // 16 MB  (4096 x 2048)
  __bf16* Wqb = (__bf16*)(ws + 16 * MB);  //  8 MB  (2048 x 2048)
  __bf16* Wkb = (__bf16*)(ws + 24 * MB);  //  2 MB  (512 x 2048)
  __bf16* Wvb = (__bf16*)(ws + 26 * MB);  //  2 MB
  __bf16* Wob = (__bf16*)(ws + 28 * MB);  //  8 MB
  __bf16* Qb  = (__bf16*)(ws + 36 * MB);  // 16 MB  (4096 x 2048)
  __bf16* Kb  = (__bf16*)(ws + 52 * MB);  //  4 MB  (4096 x 512)
  __bf16* Vb  = (__bf16*)(ws + 56 * MB);  //  4 MB
  __bf16* Vtb = (__bf16*)(ws + 60 * MB);  //  4 MB  (1024 x 2048)
  __bf16* Ctx = (__bf16*)(ws + 64 * MB);  // 16 MB  (4096 x 2048)

  // fused conversion: 18.9M elems / 8 per thread / 256 per block = 9216 blocks
  cvt_all<<<9216, 256, 0, stream>>>(x, Wq, Wk, Wv, Wo, xb, Wqb, Wkb, Wvb, Wob);

  // fused QKV projection: (4096x2048) x [Wq;Wk;Wv]^T, N = 2048+512+512
  gemm_bt<false><<<(4096 / 128) * (3072 / 128), 256, 0, stream>>>(
      xb, Wqb, Wkb, Wvb, (void*)Qb, (void*)Kb, (void*)Vb, 3072, 2048, 2560, 2048);

  transpose_v<<<512, 256, 0, stream>>>(Vb, Vtb);

  attn<<<1024, 256, 0, stream>>>(Qb, Kb, Vtb, Ctx);

  // output projection: (4096x2048) x (2048x2048)^T -> fp32
  gemm_bt<true><<<(4096 / 128) * (2048 / 128), 256, 0, stream>>>(
      Ctx, Wob, Wob, Wob, (void*)out, (void*)out, (void*)out, 2048, 2048, 2048, 2048);
}

// Round 9
// 200.316 us; speedup vs baseline: 1.5514x; 1.1569x over previous
//
#include <hip/hip_runtime.h>
#include <stdint.h>

#define S_LEN 2048
#define DMODEL 2048
#define NQH 16
#define NKVH 4
#define HDK 128

typedef __bf16 bf16x8 __attribute__((ext_vector_type(8)));
typedef float f32x4 __attribute__((ext_vector_type(4)));
typedef float f32x16 __attribute__((ext_vector_type(16)));

__device__ __forceinline__ void async16(const void* g, void* l) {
  __builtin_amdgcn_global_load_lds((const __attribute__((address_space(1))) void*)g,
                                   (__attribute__((address_space(3))) void*)l,
                                   16, 0, 0);
}

__device__ __forceinline__ f32x4 mfma16(bf16x8 a, bf16x8 b, f32x4 c) {
  return __builtin_amdgcn_mfma_f32_16x16x32_bf16(a, b, c, 0, 0, 0);
}
__device__ __forceinline__ f32x16 mfma32(bf16x8 a, bf16x8 b, f32x16 c) {
  return __builtin_amdgcn_mfma_f32_32x32x16_bf16(a, b, c, 0, 0, 0);
}
__device__ __forceinline__ uint32_t pkbf16(float lo, float hi) {
  uint32_t r;
  asm("v_cvt_pk_bf16_f32 %0, %1, %2" : "=v"(r) : "v"(lo), "v"(hi));
  return r;
}

// ---------------- fused fp32 -> bf16 conversion (all 5 tensors) ----------------
__global__ __launch_bounds__(256) void cvt_all(
    const float* __restrict__ i0, const float* __restrict__ i1,
    const float* __restrict__ i2, const float* __restrict__ i3,
    const float* __restrict__ i4, __bf16* __restrict__ o0,
    __bf16* __restrict__ o1, __bf16* __restrict__ o2, __bf16* __restrict__ o3,
    __bf16* __restrict__ o4) {
  int v = blockIdx.x * 256 + threadIdx.x;  // vec8 index; total 2359296
  const float* in;
  __bf16* out;
  int base;
  if (v < 1048576)      { in = i0; out = o0; base = 0; }
  else if (v < 1572864) { in = i1; out = o1; base = 1048576; }
  else if (v < 1703936) { in = i2; out = o2; base = 1572864; }
  else if (v < 1835008) { in = i3; out = o3; base = 1703936; }
  else                  { in = i4; out = o4; base = 1835008; }
  int i = (v - base) * 8;
  const float4* p = (const float4*)(in + i);
  float4 a = p[0], b = p[1];
  bf16x8 o;
  o[0] = (__bf16)a.x; o[1] = (__bf16)a.y; o[2] = (__bf16)a.z; o[3] = (__bf16)a.w;
  o[4] = (__bf16)b.x; o[5] = (__bf16)b.y; o[6] = (__bf16)b.z; o[7] = (__bf16)b.w;
  *(bf16x8*)(out + i) = o;
}

// ---------------- GEMM: C[m,n] = sum_k A[m,k]*B[n,k], 3-way N-routed ----------------
template <bool F32OUT>
__global__ __launch_bounds__(256) void gemm_bt(const __bf16* __restrict__ A,
                                               const __bf16* __restrict__ B0,
                                               const __bf16* __restrict__ B1,
                                               const __bf16* __restrict__ B2,
                                               void* __restrict__ C0,
                                               void* __restrict__ C1,
                                               void* __restrict__ C2,
                                               int Ntot, int Ns1, int Ns2, int K) {
  int nbn = Ntot >> 7;
  int nwg = gridDim.x;
  int bid = blockIdx.x;
  int bx = (bid & 7) * (nwg >> 3) + (bid >> 3);  // XCD swizzle (nwg % 8 == 0)
  int m0 = (bx / nbn) << 7;
  int n0g = (bx % nbn) << 7;
  const __bf16* B;
  void* C;
  int n0, Nc;
  if (n0g < Ns1)      { B = B0; C = C0; n0 = n0g;       Nc = Ns1; }
  else if (n0g < Ns2) { B = B1; C = C1; n0 = n0g - Ns1; Nc = Ns2 - Ns1; }
  else                { B = B2; C = C2; n0 = n0g - Ns2; Nc = Ntot - Ns2; }

  __shared__ __align__(16) uint8_t As[16384]; // [128][64] bf16, XOR-swizzled
  __shared__ __align__(16) uint8_t Bs[16384];

  int t = threadIdx.x, lane = t & 63, w = t >> 6;
  int wr = w >> 1, wc = w & 1;
  f32x4 acc[4][4] = {};

  for (int k0 = 0; k0 < K; k0 += 64) {
#pragma unroll
    for (int i = 0; i < 4; ++i) {
      int c = (i << 8) + t;
      int row = c >> 3;
      int colb = ((c & 7) << 4) ^ ((row & 7) << 4);
      async16((const uint8_t*)(A + (size_t)(m0 + row) * K + k0) + colb, As + c * 16);
      async16((const uint8_t*)(B + (size_t)(n0 + row) * K + k0) + colb, Bs + c * 16);
    }
    __syncthreads();
#pragma unroll
    for (int ks = 0; ks < 2; ++ks) {
      bf16x8 af[4], bfr[4];
#pragma unroll
      for (int m = 0; m < 4; ++m) {
        int row = wr * 64 + m * 16 + (lane & 15);
        int colb = ((ks << 6) + ((lane >> 4) << 4)) ^ ((row & 7) << 4);
        af[m] = *(const bf16x8*)(As + row * 128 + colb);
      }
#pragma unroll
      for (int n = 0; n < 4; ++n) {
        int row = wc * 64 + n * 16 + (lane & 15);
        int colb = ((ks << 6) + ((lane >> 4) << 4)) ^ ((row & 7) << 4);
        bfr[n] = *(const bf16x8*)(Bs + row * 128 + colb);
      }
      __builtin_amdgcn_s_setprio(1);
#pragma unroll
      for (int m = 0; m < 4; ++m)
#pragma unroll
        for (int n = 0; n < 4; ++n)
          acc[m][n] = mfma16(af[m], bfr[n], acc[m][n]);
      __builtin_amdgcn_s_setprio(0);
    }
    __syncthreads();
  }
#pragma unroll
  for (int m = 0; m < 4; ++m)
#pragma unroll
    for (int n = 0; n < 4; ++n)
#pragma unroll
      for (int j = 0; j < 4; ++j) {
        int mg = m0 + wr * 64 + m * 16 + ((lane >> 4) << 2) + j;
        int ng = n0 + wc * 64 + n * 16 + (lane & 15);
        float v = acc[m][n][j];
        if (F32OUT) ((float*)C)[(size_t)mg * Nc + ng] = v;
        else        ((__bf16*)C)[(size_t)mg * Nc + ng] = (__bf16)v;
      }
}

// ---------------- V transpose: (B*S, 512) -> Vt[(b*4+kvh)*128 + d][s] ----------------
__global__ __launch_bounds__(256) void transpose_v(const __bf16* __restrict__ V,
                                                   __bf16* __restrict__ Vt) {
  int bid = blockIdx.x;
  int dt = bid & 1, st = (bid >> 1) & 31, kvh = (bid >> 6) & 3, b = bid >> 8;
  __shared__ __align__(16) __bf16 tile[64][72];
  int t = threadIdx.x;
#pragma unroll
  for (int i = 0; i < 2; ++i) {
    int c = (i << 8) + t;
    int sr = c >> 3, cb = (c & 7) << 3;
    bf16x8 v = *(const bf16x8*)(V + (size_t)(b * S_LEN + st * 64 + sr) * 512 +
                                kvh * HDK + dt * 64 + cb);
    *(bf16x8*)(&tile[sr][cb]) = v;
  }
  __syncthreads();
#pragma unroll
  for (int i = 0; i < 2; ++i) {
    int c = (i << 8) + t;
    int dr = c >> 3, sb = (c & 7) << 3;
    bf16x8 o;
#pragma unroll
    for (int j = 0; j < 8; ++j) o[j] = tile[sb + j][dr];
    *(bf16x8*)(Vt + (size_t)((b * NKVH + kvh) * HDK + dt * 64 + dr) * S_LEN +
               st * 64 + sb) = o;
  }
}

// ---------------- causal GQA flash attention, 32x32 swapped-QK^T ----------------
// 4 waves x 32 q-rows (QBLK=128), KVBLK=64, in-register softmax (lane owns q=lane&31).
// K/V double-buffered in LDS (64KB -> 2 blocks/CU, the structural cap for this shape).
__global__ __launch_bounds__(256, 2) void attn(const __bf16* __restrict__ Q,
                                               const __bf16* __restrict__ Kx,
                                               const __bf16* __restrict__ Vt,
                                               __bf16* __restrict__ Ctx) {
  int bid0 = blockIdx.x;
  int bid = ((bid0 & 7) << 6) | (bid0 >> 3);  // XCD swizzle: 512 blocks, 64/XCD
  int qt = 15 - (bid & 15);
  int h = (bid >> 4) & 15;
  int b = bid >> 8;
  int kvh = h >> 2;
  int q0 = qt << 7;
  int t = threadIdx.x, lane = t & 63, w = t >> 6;
  int qr = lane & 31;   // own q-row within wave
  int hi = lane >> 5;
  int qwb = q0 + (w << 5);

  __shared__ __align__(16) uint8_t Ks[2][16384];  // [64 key][128 d] bf16, swizzled
  __shared__ __align__(16) uint8_t Vs[2][16384];  // [128 d][64 key] bf16, swizzled

  const __bf16* kbase = Kx + (size_t)b * S_LEN * 512 + kvh * HDK;
  const __bf16* vbase = Vt + (size_t)(b * NKVH + kvh) * HDK * S_LEN;

  auto stage = [&](int kt, int bufi) {
#pragma unroll
    for (int i = 0; i < 4; ++i) {
      int c = (i << 8) + t;
      int krow = c >> 4;
      int kcolb = ((c & 15) << 4) ^ ((krow & 7) << 4);
      async16((const uint8_t*)(kbase + (size_t)((kt << 6) + krow) * 512) + kcolb,
              Ks[bufi] + c * 16);
      int vrow = c >> 3;
      int vcolb = ((c & 7) << 4) ^ ((vrow & 7) << 4);
      async16((const uint8_t*)(vbase + (size_t)vrow * S_LEN + (kt << 6)) + vcolb,
              Vs[bufi] + c * 16);
    }
  };

  int NT = (qt << 1) + 2;
  stage(0, 0);

  // Q fragments: lane holds Q[q = qwb+qr][d = dk*16 + hi*8 + j]
  bf16x8 qf[8];
  {
    const __bf16* qrow = Q + (size_t)(b * S_LEN + qwb + qr) * DMODEL + h * HDK + hi * 8;
#pragma unroll
    for (int dk = 0; dk < 8; ++dk) qf[dk] = *(const bf16x8*)(qrow + dk * 16);
  }
  __syncthreads();  // stage(0) drained

  const float NEG = -3.0e38f;
  const float SC = 0.08838834764831845f;  // 1/sqrt(128)
  float m_run = NEG, l_run = 0.f;
  f32x16 acc[4] = {};  // O[q][d], 4 d-tiles of 32

  for (int kt = 0; kt < NT; ++kt) {
    int cur = kt & 1;
    if (kt + 1 < NT) stage(kt + 1, cur ^ 1);
    int k0 = kt << 6;
    if (k0 <= qwb + 31) {  // wave-uniform skip of fully-masked tiles
      const uint8_t* ks = Ks[cur];
      const uint8_t* vs = Vs[cur];

      // S^T = K Q^T : D[key][q], col=q=lane&31, row=(r&3)+8*(r>>2)+4*hi
      f32x16 st0 = {}, st1 = {};
      __builtin_amdgcn_s_setprio(1);
#pragma unroll
      for (int dk = 0; dk < 8; ++dk) {
        int cb = (dk << 5) + (hi << 4);
        int swz = (qr & 7) << 4;
        bf16x8 kf0 = *(const bf16x8*)(ks + qr * 256 + (cb ^ swz));
        st0 = mfma32(kf0, qf[dk], st0);
        bf16x8 kf1 = *(const bf16x8*)(ks + (32 + qr) * 256 + (cb ^ swz));
        st1 = mfma32(kf1, qf[dk], st1);
      }
      __builtin_amdgcn_s_setprio(0);

      // causal mask (diagonal-adjacent tiles only)
      if (k0 + 63 > qwb) {
#pragma unroll
        for (int r = 0; r < 16; ++r) {
          int kl = (r & 3) + ((r >> 2) << 3) + (hi << 2);
          st0[r] = (k0 + kl > qwb + qr) ? NEG : st0[r];
          st1[r] = (k0 + 32 + kl > qwb + qr) ? NEG : st1[r];
        }
      }

      // row max: explicit binary tree (depth 5) + one cross-half merge
      float tm[16];
#pragma unroll
      for (int r = 0; r < 16; ++r) tm[r] = fmaxf(st0[r], st1[r]);
#pragma unroll
      for (int s = 8; s > 0; s >>= 1)
#pragma unroll
        for (int r = 0; r < s; ++r) tm[r] = fmaxf(tm[r], tm[r + s]);
      float mx = fmaxf(tm[0], __shfl_xor(tm[0], 32, 64));

      // defer-max: rescale only when max grows by >8/SC in raw score units
      if (__any(mx > m_run + 90.52f)) {
        float mn = fmaxf(m_run, mx);
        float al = __expf((m_run - mn) * SC);
        l_run *= al;
        m_run = mn;
#pragma unroll
        for (int i = 0; i < 16; ++i) {
          float alr = __shfl(al, (i & 3) + ((i >> 2) << 3) + (hi << 2), 64);
          acc[0][i] *= alr; acc[1][i] *= alr; acc[2][i] *= alr; acc[3][i] *= alr;
        }
      }

      float mSC = m_run * SC;
      float p0[16], p1[16];
#pragma unroll
      for (int r = 0; r < 16; ++r) p0[r] = __expf(fmaf(st0[r], SC, -mSC));
#pragma unroll
      for (int r = 0; r < 16; ++r) p1[r] = __expf(fmaf(st1[r], SC, -mSC));
      // row sum: binary tree + one cross-half merge
      float ts[16];
#pragma unroll
      for (int r = 0; r < 16; ++r) ts[r] = p0[r] + p1[r];
#pragma unroll
      for (int s = 8; s > 0; s >>= 1)
#pragma unroll
        for (int r = 0; r < s; ++r) ts[r] += ts[r + s];
      l_run += ts[0] + __shfl_xor(ts[0], 32, 64);

      // pack P to bf16 and redistribute to PV A-frag layout (shfl_xor + select)
      uint32_t wd0[4][2], wd1[4][2];
#pragma unroll
      for (int g = 0; g < 4; ++g) {
        wd0[g][0] = pkbf16(p0[4 * g + 0], p0[4 * g + 1]);
        wd0[g][1] = pkbf16(p0[4 * g + 2], p0[4 * g + 3]);
        wd1[g][0] = pkbf16(p1[4 * g + 0], p1[4 * g + 1]);
        wd1[g][1] = pkbf16(p1[4 * g + 2], p1[4 * g + 3]);
      }
      bf16x8 pa[4];
#define PEXCH(WD, IDX0, IDX1)                                                  \
      {                                                                        \
        uint32_t s0 = hi ? WD[0][0] : WD[1][0];                                \
        uint32_t s1 = hi ? WD[0][1] : WD[1][1];                                \
        uint32_t s2 = hi ? WD[2][0] : WD[3][0];                                \
        uint32_t s3 = hi ? WD[2][1] : WD[3][1];                                \
        uint32_t r0 = (uint32_t)__shfl_xor((int)s0, 32, 64);                   \
        uint32_t r1 = (uint32_t)__shfl_xor((int)s1, 32, 64);                   \
        uint32_t r2 = (uint32_t)__shfl_xor((int)s2, 32, 64);                   \
        uint32_t r3 = (uint32_t)__shfl_xor((int)s3, 32, 64);                   \
        union { bf16x8 v; uint32_t u[4]; } fa, fb;                             \
        fa.u[0] = hi ? r0 : WD[0][0];                                          \
        fa.u[1] = hi ? r1 : WD[0][1];                                          \
        fa.u[2] = hi ? WD[1][0] : r0;                                          \
        fa.u[3] = hi ? WD[1][1] : r1;                                          \
        fb.u[0] = hi ? r2 : WD[2][0];                                          \
        fb.u[1] = hi ? r3 : WD[2][1];                                          \
        fb.u[2] = hi ? WD[3][0] : r2;                                          \
        fb.u[3] = hi ? WD[3][1] : r3;                                          \
        pa[IDX0] = fa.v;                                                       \
        pa[IDX1] = fb.v;                                                       \
      }
      PEXCH(wd0, 0, 1)
      PEXCH(wd1, 2, 3)
#undef PEXCH

      // O += P V : A=pa (P[q][k]), B=V[k][d] from d-major Vt_lds
      __builtin_amdgcn_s_setprio(1);
#pragma unroll
      for (int dt = 0; dt < 4; ++dt) {
        int row = (dt << 5) + qr;
        int swz = (row & 7) << 4;
#pragma unroll
        for (int kc = 0; kc < 4; ++kc) {
          bf16x8 vf = *(const bf16x8*)(vs + row * 128 + (((kc << 5) + (hi << 4)) ^ swz));
          acc[dt] = mfma32(pa[kc], vf, acc[dt]);
        }
      }
      __builtin_amdgcn_s_setprio(0);
    }
    __syncthreads();  // single barrier: drains next-tile stage, releases cur buf
  }

  // epilogue: normalize by per-row l, write out
#pragma unroll
  for (int i = 0; i < 16; ++i) {
    int rm = (i & 3) + ((i >> 2) << 3) + (hi << 2);
    float lr = __shfl(l_run, rm, 64);
    float inv = 1.0f / lr;
    size_t rowoff = (size_t)(b * S_LEN + qwb + rm) * DMODEL + h * HDK + qr;
#pragma unroll
    for (int dt = 0; dt < 4; ++dt)
      Ctx[rowoff + (dt << 5)] = (__bf16)(acc[dt][i] * inv);
  }
}

// ---------------- launch ----------------
extern "C" void kernel_launch(void* const* d_in, const int* in_sizes, int n_in,
                              void* d_out, int out_size, void* d_ws, size_t ws_size,
                              hipStream_t stream) {
  const float* x  = (const float*)d_in[0];
  const float* Wq = (const float*)d_in[1];
  const float* Wk = (const float*)d_in[2];
  const float* Wv = (const float*)d_in[3];
  const float* Wo = (const float*)d_in[4];
  float* out = (float*)d_out;

  const size_t MB = 1024 * 1024;
  uint8_t* ws = (uint8_t*)d_ws;
  __bf16* xb  = (__bf16*)(ws + 0 * MB);   // 16 MB  (4096 x 2048)
  __bf16* Wqb = (__bf16*)(ws + 16 * MB);  //  8 MB  (2048 x 2048)
  __bf16* Wkb = (__bf16*)(ws + 24 * MB);  //  2 MB  (512 x 2048)
  __bf16* Wvb = (__bf16*)(ws + 26 * MB);  //  2 MB
  __bf16* Wob = (__bf16*)(ws + 28 * MB);  //  8 MB
  __bf16* Qb  = (__bf16*)(ws + 36 * MB);  // 16 MB  (4096 x 2048)
  __bf16* Kb  = (__bf16*)(ws + 52 * MB);  //  4 MB  (4096 x 512)
  __bf16* Vb  = (__bf16*)(ws + 56 * MB);  //  4 MB
  __bf16* Vtb = (__bf16*)(ws + 60 * MB);  //  4 MB  (1024 x 2048)
  __bf16* Ctx = (__bf16*)(ws + 64 * MB);  // 16 MB  (4096 x 2048)

  // fused conversion: 18.9M elems / 8 per thread / 256 per block = 9216 blocks
  cvt_all<<<9216, 256, 0, stream>>>(x, Wq, Wk, Wv, Wo, xb, Wqb, Wkb, Wvb, Wob);

  // fused QKV projection: (4096x2048) x [Wq;Wk;Wv]^T, N = 2048+512+512
  gemm_bt<false><<<(4096 / 128) * (3072 / 128), 256, 0, stream>>>(
      xb, Wqb, Wkb, Wvb, (void*)Qb, (void*)Kb, (void*)Vb, 3072, 2048, 2560, 2048);

  transpose_v<<<512, 256, 0, stream>>>(Vb, Vtb);

  attn<<<512, 256, 0, stream>>>(Qb, Kb, Vtb, Ctx);

  // output projection: (4096x2048) x (2048x2048)^T -> fp32
  gemm_bt<true><<<(4096 / 128) * (2048 / 128), 256, 0, stream>>>(
      Ctx, Wob, Wob, Wob, (void*)out, (void*)out, (void*)out, 2048, 2048, 2048, 2048);
}

// Round 10
// 198.254 us; speedup vs baseline: 1.5675x; 1.0104x over previous
//
#include <hip/hip_runtime.h>
#include <stdint.h>

#define S_LEN 2048
#define DMODEL 2048
#define NQH 16
#define NKVH 4
#define HDK 128

typedef __bf16 bf16x8 __attribute__((ext_vector_type(8)));
typedef float f32x4 __attribute__((ext_vector_type(4)));
typedef float f32x16 __attribute__((ext_vector_type(16)));

__device__ __forceinline__ void async16(const void* g, void* l) {
  __builtin_amdgcn_global_load_lds((const __attribute__((address_space(1))) void*)g,
                                   (__attribute__((address_space(3))) void*)l,
                                   16, 0, 0);
}

__device__ __forceinline__ f32x4 mfma16(bf16x8 a, bf16x8 b, f32x4 c) {
  return __builtin_amdgcn_mfma_f32_16x16x32_bf16(a, b, c, 0, 0, 0);
}
__device__ __forceinline__ f32x16 mfma32(bf16x8 a, bf16x8 b, f32x16 c) {
  return __builtin_amdgcn_mfma_f32_32x32x16_bf16(a, b, c, 0, 0, 0);
}
__device__ __forceinline__ uint32_t pkbf16(float lo, float hi) {
  uint32_t r;
  asm("v_cvt_pk_bf16_f32 %0, %1, %2" : "=v"(r) : "v"(lo), "v"(hi));
  return r;
}

// ---------------- fused fp32 -> bf16 conversion (all 5 tensors) ----------------
__global__ __launch_bounds__(256) void cvt_all(
    const float* __restrict__ i0, const float* __restrict__ i1,
    const float* __restrict__ i2, const float* __restrict__ i3,
    const float* __restrict__ i4, __bf16* __restrict__ o0,
    __bf16* __restrict__ o1, __bf16* __restrict__ o2, __bf16* __restrict__ o3,
    __bf16* __restrict__ o4) {
  int v = blockIdx.x * 256 + threadIdx.x;  // vec8 index; total 2359296
  const float* in;
  __bf16* out;
  int base;
  if (v < 1048576)      { in = i0; out = o0; base = 0; }
  else if (v < 1572864) { in = i1; out = o1; base = 1048576; }
  else if (v < 1703936) { in = i2; out = o2; base = 1572864; }
  else if (v < 1835008) { in = i3; out = o3; base = 1703936; }
  else                  { in = i4; out = o4; base = 1835008; }
  int i = (v - base) * 8;
  const float4* p = (const float4*)(in + i);
  float4 a = p[0], b = p[1];
  bf16x8 o;
  o[0] = (__bf16)a.x; o[1] = (__bf16)a.y; o[2] = (__bf16)a.z; o[3] = (__bf16)a.w;
  o[4] = (__bf16)b.x; o[5] = (__bf16)b.y; o[6] = (__bf16)b.z; o[7] = (__bf16)b.w;
  *(bf16x8*)(out + i) = o;
}

// ---------------- GEMM: C[m,n] = sum_k A[m,k]*B[n,k], 3-way N-routed ----------------
template <bool F32OUT>
__global__ __launch_bounds__(256) void gemm_bt(const __bf16* __restrict__ A,
                                               const __bf16* __restrict__ B0,
                                               const __bf16* __restrict__ B1,
                                               const __bf16* __restrict__ B2,
                                               void* __restrict__ C0,
                                               void* __restrict__ C1,
                                               void* __restrict__ C2,
                                               int Ntot, int Ns1, int Ns2, int K) {
  int nbn = Ntot >> 7;
  int nwg = gridDim.x;
  int bid = blockIdx.x;
  int bx = (bid & 7) * (nwg >> 3) + (bid >> 3);  // XCD swizzle (nwg % 8 == 0)
  int m0 = (bx / nbn) << 7;
  int n0g = (bx % nbn) << 7;
  const __bf16* B;
  void* C;
  int n0, Nc;
  if (n0g < Ns1)      { B = B0; C = C0; n0 = n0g;       Nc = Ns1; }
  else if (n0g < Ns2) { B = B1; C = C1; n0 = n0g - Ns1; Nc = Ns2 - Ns1; }
  else                { B = B2; C = C2; n0 = n0g - Ns2; Nc = Ntot - Ns2; }

  __shared__ __align__(16) uint8_t As[16384]; // [128][64] bf16, XOR-swizzled
  __shared__ __align__(16) uint8_t Bs[16384];

  int t = threadIdx.x, lane = t & 63, w = t >> 6;
  int wr = w >> 1, wc = w & 1;
  f32x4 acc[4][4] = {};

  for (int k0 = 0; k0 < K; k0 += 64) {
#pragma unroll
    for (int i = 0; i < 4; ++i) {
      int c = (i << 8) + t;
      int row = c >> 3;
      int colb = ((c & 7) << 4) ^ ((row & 7) << 4);
      async16((const uint8_t*)(A + (size_t)(m0 + row) * K + k0) + colb, As + c * 16);
      async16((const uint8_t*)(B + (size_t)(n0 + row) * K + k0) + colb, Bs + c * 16);
    }
    __syncthreads();
#pragma unroll
    for (int ks = 0; ks < 2; ++ks) {
      bf16x8 af[4], bfr[4];
#pragma unroll
      for (int m = 0; m < 4; ++m) {
        int row = wr * 64 + m * 16 + (lane & 15);
        int colb = ((ks << 6) + ((lane >> 4) << 4)) ^ ((row & 7) << 4);
        af[m] = *(const bf16x8*)(As + row * 128 + colb);
      }
#pragma unroll
      for (int n = 0; n < 4; ++n) {
        int row = wc * 64 + n * 16 + (lane & 15);
        int colb = ((ks << 6) + ((lane >> 4) << 4)) ^ ((row & 7) << 4);
        bfr[n] = *(const bf16x8*)(Bs + row * 128 + colb);
      }
      __builtin_amdgcn_s_setprio(1);
#pragma unroll
      for (int m = 0; m < 4; ++m)
#pragma unroll
        for (int n = 0; n < 4; ++n)
          acc[m][n] = mfma16(af[m], bfr[n], acc[m][n]);
      __builtin_amdgcn_s_setprio(0);
    }
    __syncthreads();
  }
#pragma unroll
  for (int m = 0; m < 4; ++m)
#pragma unroll
    for (int n = 0; n < 4; ++n)
#pragma unroll
      for (int j = 0; j < 4; ++j) {
        int mg = m0 + wr * 64 + m * 16 + ((lane >> 4) << 2) + j;
        int ng = n0 + wc * 64 + n * 16 + (lane & 15);
        float v = acc[m][n][j];
        if (F32OUT) ((float*)C)[(size_t)mg * Nc + ng] = v;
        else        ((__bf16*)C)[(size_t)mg * Nc + ng] = (__bf16)v;
      }
}

// ---------------- V transpose: (B*S, 512) -> Vt[(b*4+kvh)*128 + d][s] ----------------
__global__ __launch_bounds__(256) void transpose_v(const __bf16* __restrict__ V,
                                                   __bf16* __restrict__ Vt) {
  int bid = blockIdx.x;
  int dt = bid & 1, st = (bid >> 1) & 31, kvh = (bid >> 6) & 3, b = bid >> 8;
  __shared__ __align__(16) __bf16 tile[64][72];
  int t = threadIdx.x;
#pragma unroll
  for (int i = 0; i < 2; ++i) {
    int c = (i << 8) + t;
    int sr = c >> 3, cb = (c & 7) << 3;
    bf16x8 v = *(const bf16x8*)(V + (size_t)(b * S_LEN + st * 64 + sr) * 512 +
                                kvh * HDK + dt * 64 + cb);
    *(bf16x8*)(&tile[sr][cb]) = v;
  }
  __syncthreads();
#pragma unroll
  for (int i = 0; i < 2; ++i) {
    int c = (i << 8) + t;
    int dr = c >> 3, sb = (c & 7) << 3;
    bf16x8 o;
#pragma unroll
    for (int j = 0; j < 8; ++j) o[j] = tile[sb + j][dr];
    *(bf16x8*)(Vt + (size_t)((b * NKVH + kvh) * HDK + dt * 64 + dr) * S_LEN +
               st * 64 + sb) = o;
  }
}

// ---------------- causal GQA flash attention, 32x32 swapped-QK^T ----------------
// 4 waves x 32 q-rows (QBLK=128), KVBLK=64, in-register softmax (lane owns q=lane&31).
// Zero-shuffle PV: K-axis of the PV MFMA is permuted (same pi on A and B) so each
// lane's own softmax registers ARE the A-fragment; V supplies pi via two 8B reads.
__global__ __launch_bounds__(256, 2) void attn(const __bf16* __restrict__ Q,
                                               const __bf16* __restrict__ Kx,
                                               const __bf16* __restrict__ Vt,
                                               __bf16* __restrict__ Ctx) {
  int bid0 = blockIdx.x;
  int bid = ((bid0 & 7) << 6) | (bid0 >> 3);  // XCD swizzle: 512 blocks, 64/XCD
  int qt = 15 - (bid & 15);
  int h = (bid >> 4) & 15;
  int b = bid >> 8;
  int kvh = h >> 2;
  int q0 = qt << 7;
  int t = threadIdx.x, lane = t & 63, w = t >> 6;
  int qr = lane & 31;   // own q-row within wave
  int hi = lane >> 5;
  int qwb = q0 + (w << 5);

  __shared__ __align__(16) uint8_t Ks[2][16384];  // [64 key][128 d] bf16, swizzled
  __shared__ __align__(16) uint8_t Vs[2][16384];  // [128 d][64 key] bf16, swizzled

  const __bf16* kbase = Kx + (size_t)b * S_LEN * 512 + kvh * HDK;
  const __bf16* vbase = Vt + (size_t)(b * NKVH + kvh) * HDK * S_LEN;

  auto stage = [&](int kt, int bufi) {
#pragma unroll
    for (int i = 0; i < 4; ++i) {
      int c = (i << 8) + t;
      int krow = c >> 4;
      int kcolb = ((c & 15) << 4) ^ ((krow & 7) << 4);
      async16((const uint8_t*)(kbase + (size_t)((kt << 6) + krow) * 512) + kcolb,
              Ks[bufi] + c * 16);
      int vrow = c >> 3;
      int vcolb = ((c & 7) << 4) ^ ((vrow & 7) << 4);
      async16((const uint8_t*)(vbase + (size_t)vrow * S_LEN + (kt << 6)) + vcolb,
              Vs[bufi] + c * 16);
    }
  };

  int NT = (qt << 1) + 2;
  stage(0, 0);

  // Q fragments: lane holds Q[q = qwb+qr][d = dk*16 + hi*8 + j]
  bf16x8 qf[8];
  {
    const __bf16* qrow = Q + (size_t)(b * S_LEN + qwb + qr) * DMODEL + h * HDK + hi * 8;
#pragma unroll
    for (int dk = 0; dk < 8; ++dk) qf[dk] = *(const bf16x8*)(qrow + dk * 16);
  }
  __syncthreads();  // stage(0) drained

  const float NEG = -3.0e38f;
  const float SC = 0.08838834764831845f;  // 1/sqrt(128)
  float m_run = NEG, l_run = 0.f;         // l_run: own-half partial until epilogue
  f32x16 acc[4] = {};  // O[q][d], 4 d-tiles of 32

  for (int kt = 0; kt < NT; ++kt) {
    int cur = kt & 1;
    if (kt + 1 < NT) stage(kt + 1, cur ^ 1);
    int k0 = kt << 6;
    if (k0 <= qwb + 31) {  // wave-uniform skip of fully-masked tiles
      const uint8_t* ks = Ks[cur];
      const uint8_t* vs = Vs[cur];

      // S^T = K Q^T : D[key][q], col=q=lane&31, row=(r&3)+8*(r>>2)+4*hi
      f32x16 st0 = {}, st1 = {};
      __builtin_amdgcn_s_setprio(1);
#pragma unroll
      for (int dk = 0; dk < 8; ++dk) {
        int cb = (dk << 5) + (hi << 4);
        int swz = (qr & 7) << 4;
        bf16x8 kf0 = *(const bf16x8*)(ks + qr * 256 + (cb ^ swz));
        st0 = mfma32(kf0, qf[dk], st0);
        bf16x8 kf1 = *(const bf16x8*)(ks + (32 + qr) * 256 + (cb ^ swz));
        st1 = mfma32(kf1, qf[dk], st1);
      }
      __builtin_amdgcn_s_setprio(0);

      // causal mask (diagonal-adjacent tiles only)
      if (k0 + 63 > qwb) {
#pragma unroll
        for (int r = 0; r < 16; ++r) {
          int kl = (r & 3) + ((r >> 2) << 3) + (hi << 2);
          st0[r] = (k0 + kl > qwb + qr) ? NEG : st0[r];
          st1[r] = (k0 + 32 + kl > qwb + qr) ? NEG : st1[r];
        }
      }

      // row max: explicit binary tree (depth 5) + one cross-half merge
      float tm[16];
#pragma unroll
      for (int r = 0; r < 16; ++r) tm[r] = fmaxf(st0[r], st1[r]);
#pragma unroll
      for (int s = 8; s > 0; s >>= 1)
#pragma unroll
        for (int r = 0; r < s; ++r) tm[r] = fmaxf(tm[r], tm[r + s]);
      float mx = fmaxf(tm[0], __shfl_xor(tm[0], 32, 64));

      // defer-max: rescale only when max grows by >8/SC in raw score units
      if (__any(mx > m_run + 90.52f)) {
        float mn = fmaxf(m_run, mx);
        float al = __expf((m_run - mn) * SC);
        l_run *= al;
        m_run = mn;
#pragma unroll
        for (int i = 0; i < 16; ++i) {
          float alr = __shfl(al, (i & 3) + ((i >> 2) << 3) + (hi << 2), 64);
          acc[0][i] *= alr; acc[1][i] *= alr; acc[2][i] *= alr; acc[3][i] *= alr;
        }
      }

      float mSC = m_run * SC;
      float p0[16], p1[16];
#pragma unroll
      for (int r = 0; r < 16; ++r) p0[r] = __expf(fmaf(st0[r], SC, -mSC));
#pragma unroll
      for (int r = 0; r < 16; ++r) p1[r] = __expf(fmaf(st1[r], SC, -mSC));
      // row sum: binary tree; cross-half merge deferred to epilogue (additive)
      float ts[16];
#pragma unroll
      for (int r = 0; r < 16; ++r) ts[r] = p0[r] + p1[r];
#pragma unroll
      for (int s = 8; s > 0; s >>= 1)
#pragma unroll
        for (int r = 0; r < s; ++r) ts[r] += ts[r + s];
      l_run += ts[0];

      // zero-shuffle A-fragments: pi(hi*8+j) = (j&3)+8*(j>>2)+4*hi matches the
      // QK^T C/D key ownership -> own p regs pack directly into pa[kc].
      bf16x8 pa[4];
      {
        union { bf16x8 v; uint32_t u[4]; } t0, t1, t2, t3;
#pragma unroll
        for (int i = 0; i < 4; ++i) {
          t0.u[i] = pkbf16(p0[2 * i], p0[2 * i + 1]);
          t1.u[i] = pkbf16(p0[8 + 2 * i], p0[9 + 2 * i]);
          t2.u[i] = pkbf16(p1[2 * i], p1[2 * i + 1]);
          t3.u[i] = pkbf16(p1[8 + 2 * i], p1[9 + 2 * i]);
        }
        pa[0] = t0.v; pa[1] = t1.v; pa[2] = t2.v; pa[3] = t3.v;
      }

      // O += P V : B-fragment supplies V[pi(k)][d] via two 8B LDS reads:
      // keys {kc*16+4hi+0..3} and {kc*16+8+4hi+0..3} of d-row (dt*32+qr).
      __builtin_amdgcn_s_setprio(1);
#pragma unroll
      for (int dt = 0; dt < 4; ++dt) {
        int row = (dt << 5) + qr;
        int rs7 = row & 7;
#pragma unroll
        for (int kc = 0; kc < 4; ++kc) {
          int a1 = ((((kc << 1) | 0) ^ rs7) << 4) + (hi << 3);
          int a2 = ((((kc << 1) | 1) ^ rs7) << 4) + (hi << 3);
          union { bf16x8 v; uint64_t q[2]; } vfu;
          vfu.q[0] = *(const uint64_t*)(vs + row * 128 + a1);
          vfu.q[1] = *(const uint64_t*)(vs + row * 128 + a2);
          acc[dt] = mfma32(pa[kc], vfu.v, acc[dt]);
        }
      }
      __builtin_amdgcn_s_setprio(0);
    }
    __syncthreads();  // single barrier: drains next-tile stage, releases cur buf
  }

  // epilogue: merge l halves once, normalize by per-row l, write out
  l_run += __shfl_xor(l_run, 32, 64);
#pragma unroll
  for (int i = 0; i < 16; ++i) {
    int rm = (i & 3) + ((i >> 2) << 3) + (hi << 2);
    float lr = __shfl(l_run, rm, 64);
    float inv = 1.0f / lr;
    size_t rowoff = (size_t)(b * S_LEN + qwb + rm) * DMODEL + h * HDK + qr;
#pragma unroll
    for (int dt = 0; dt < 4; ++dt)
      Ctx[rowoff + (dt << 5)] = (__bf16)(acc[dt][i] * inv);
  }
}

// ---------------- launch ----------------
extern "C" void kernel_launch(void* const* d_in, const int* in_sizes, int n_in,
                              void* d_out, int out_size, void* d_ws, size_t ws_size,
                              hipStream_t stream) {
  const float* x  = (const float*)d_in[0];
  const float* Wq = (const float*)d_in[1];
  const float* Wk = (const float*)d_in[2];
  const float* Wv = (const float*)d_in[3];
  const float* Wo = (const float*)d_in[4];
  float* out = (float*)d_out;

  const size_t MB = 1024 * 1024;
  uint8_t* ws = (uint8_t*)d_ws;
  __bf16* xb  = (__bf16*)(ws + 0 * MB);   // 16 MB  (4096 x 2048)
  __bf16* Wqb = (__bf16*)(ws + 16 * MB);  //  8 MB  (2048 x 2048)
  __bf16* Wkb = (__bf16*)(ws + 24 * MB);  //  2 MB  (512 x 2048)
  __bf16* Wvb = (__bf16*)(ws + 26 * MB);  //  2 MB
  __bf16* Wob = (__bf16*)(ws + 28 * MB);  //  8 MB
  __bf16* Qb  = (__bf16*)(ws + 36 * MB);  // 16 MB  (4096 x 2048)
  __bf16* Kb  = (__bf16*)(ws + 52 * MB);  //  4 MB  (4096 x 512)
  __bf16* Vb  = (__bf16*)(ws + 56 * MB);  //  4 MB
  __bf16* Vtb = (__bf16*)(ws + 60 * MB);  //  4 MB  (1024 x 2048)
  __bf16* Ctx = (__bf16*)(ws + 64 * MB);  // 16 MB  (4096 x 2048)

  // fused conversion: 18.9M elems / 8 per thread / 256 per block = 9216 blocks
  cvt_all<<<9216, 256, 0, stream>>>(x, Wq, Wk, Wv, Wo, xb, Wqb, Wkb, Wvb, Wob);

  // fused QKV projection: (4096x2048) x [Wq;Wk;Wv]^T, N = 2048+512+512
  gemm_bt<false><<<(4096 / 128) * (3072 / 128), 256, 0, stream>>>(
      xb, Wqb, Wkb, Wvb, (void*)Qb, (void*)Kb, (void*)Vb, 3072, 2048, 2560, 2048);

  transpose_v<<<512, 256, 0, stream>>>(Vb, Vtb);

  attn<<<512, 256, 0, stream>>>(Qb, Kb, Vtb, Ctx);

  // output projection: (4096x2048) x (2048x2048)^T -> fp32
  gemm_bt<true><<<(4096 / 128) * (2048 / 128), 256, 0, stream>>>(
      Ctx, Wob, Wob, Wob, (void*)out, (void*)out, (void*)out, 2048, 2048, 2048, 2048);
}

// Round 11
// 194.102 us; speedup vs baseline: 1.6011x; 1.0214x over previous
//
#include <hip/hip_runtime.h>
#include <stdint.h>

#define S_LEN 2048
#define DMODEL 2048
#define NQH 16
#define NKVH 4
#define HDK 128

typedef __bf16 bf16x8 __attribute__((ext_vector_type(8)));
typedef float f32x4 __attribute__((ext_vector_type(4)));
typedef float f32x16 __attribute__((ext_vector_type(16)));

__device__ __forceinline__ void async16(const void* g, void* l) {
  __builtin_amdgcn_global_load_lds((const __attribute__((address_space(1))) void*)g,
                                   (__attribute__((address_space(3))) void*)l,
                                   16, 0, 0);
}

__device__ __forceinline__ f32x4 mfma16(bf16x8 a, bf16x8 b, f32x4 c) {
  return __builtin_amdgcn_mfma_f32_16x16x32_bf16(a, b, c, 0, 0, 0);
}
__device__ __forceinline__ f32x16 mfma32(bf16x8 a, bf16x8 b, f32x16 c) {
  return __builtin_amdgcn_mfma_f32_32x32x16_bf16(a, b, c, 0, 0, 0);
}
__device__ __forceinline__ uint32_t pkbf16(float lo, float hi) {
  uint32_t r;
  asm("v_cvt_pk_bf16_f32 %0, %1, %2" : "=v"(r) : "v"(lo), "v"(hi));
  return r;
}

// ---------------- fused fp32 -> bf16 conversion (all 5 tensors) ----------------
__global__ __launch_bounds__(256) void cvt_all(
    const float* __restrict__ i0, const float* __restrict__ i1,
    const float* __restrict__ i2, const float* __restrict__ i3,
    const float* __restrict__ i4, __bf16* __restrict__ o0,
    __bf16* __restrict__ o1, __bf16* __restrict__ o2, __bf16* __restrict__ o3,
    __bf16* __restrict__ o4) {
  int v = blockIdx.x * 256 + threadIdx.x;  // vec8 index; total 2359296
  const float* in;
  __bf16* out;
  int base;
  if (v < 1048576)      { in = i0; out = o0; base = 0; }
  else if (v < 1572864) { in = i1; out = o1; base = 1048576; }
  else if (v < 1703936) { in = i2; out = o2; base = 1572864; }
  else if (v < 1835008) { in = i3; out = o3; base = 1703936; }
  else                  { in = i4; out = o4; base = 1835008; }
  int i = (v - base) * 8;
  const float4* p = (const float4*)(in + i);
  float4 a = p[0], b = p[1];
  bf16x8 o;
  o[0] = (__bf16)a.x; o[1] = (__bf16)a.y; o[2] = (__bf16)a.z; o[3] = (__bf16)a.w;
  o[4] = (__bf16)b.x; o[5] = (__bf16)b.y; o[6] = (__bf16)b.z; o[7] = (__bf16)b.w;
  *(bf16x8*)(out + i) = o;
}

// ---------------- GEMM: C[m,n] = sum_k A[m,k]*B[n,k], 3-way N-routed ----------------
template <bool F32OUT>
__global__ __launch_bounds__(256) void gemm_bt(const __bf16* __restrict__ A,
                                               const __bf16* __restrict__ B0,
                                               const __bf16* __restrict__ B1,
                                               const __bf16* __restrict__ B2,
                                               void* __restrict__ C0,
                                               void* __restrict__ C1,
                                               void* __restrict__ C2,
                                               int Ntot, int Ns1, int Ns2, int K) {
  int nbn = Ntot >> 7;
  int nwg = gridDim.x;
  int bid = blockIdx.x;
  int bx = (bid & 7) * (nwg >> 3) + (bid >> 3);  // XCD swizzle (nwg % 8 == 0)
  int m0 = (bx / nbn) << 7;
  int n0g = (bx % nbn) << 7;
  const __bf16* B;
  void* C;
  int n0, Nc;
  if (n0g < Ns1)      { B = B0; C = C0; n0 = n0g;       Nc = Ns1; }
  else if (n0g < Ns2) { B = B1; C = C1; n0 = n0g - Ns1; Nc = Ns2 - Ns1; }
  else                { B = B2; C = C2; n0 = n0g - Ns2; Nc = Ntot - Ns2; }

  __shared__ __align__(16) uint8_t As[16384]; // [128][64] bf16, XOR-swizzled
  __shared__ __align__(16) uint8_t Bs[16384];

  int t = threadIdx.x, lane = t & 63, w = t >> 6;
  int wr = w >> 1, wc = w & 1;
  f32x4 acc[4][4] = {};

  for (int k0 = 0; k0 < K; k0 += 64) {
#pragma unroll
    for (int i = 0; i < 4; ++i) {
      int c = (i << 8) + t;
      int row = c >> 3;
      int colb = ((c & 7) << 4) ^ ((row & 7) << 4);
      async16((const uint8_t*)(A + (size_t)(m0 + row) * K + k0) + colb, As + c * 16);
      async16((const uint8_t*)(B + (size_t)(n0 + row) * K + k0) + colb, Bs + c * 16);
    }
    __syncthreads();
#pragma unroll
    for (int ks = 0; ks < 2; ++ks) {
      bf16x8 af[4], bfr[4];
#pragma unroll
      for (int m = 0; m < 4; ++m) {
        int row = wr * 64 + m * 16 + (lane & 15);
        int colb = ((ks << 6) + ((lane >> 4) << 4)) ^ ((row & 7) << 4);
        af[m] = *(const bf16x8*)(As + row * 128 + colb);
      }
#pragma unroll
      for (int n = 0; n < 4; ++n) {
        int row = wc * 64 + n * 16 + (lane & 15);
        int colb = ((ks << 6) + ((lane >> 4) << 4)) ^ ((row & 7) << 4);
        bfr[n] = *(const bf16x8*)(Bs + row * 128 + colb);
      }
      __builtin_amdgcn_s_setprio(1);
#pragma unroll
      for (int m = 0; m < 4; ++m)
#pragma unroll
        for (int n = 0; n < 4; ++n)
          acc[m][n] = mfma16(af[m], bfr[n], acc[m][n]);
      __builtin_amdgcn_s_setprio(0);
    }
    __syncthreads();
  }
#pragma unroll
  for (int m = 0; m < 4; ++m)
#pragma unroll
    for (int n = 0; n < 4; ++n)
#pragma unroll
      for (int j = 0; j < 4; ++j) {
        int mg = m0 + wr * 64 + m * 16 + ((lane >> 4) << 2) + j;
        int ng = n0 + wc * 64 + n * 16 + (lane & 15);
        float v = acc[m][n][j];
        if (F32OUT) ((float*)C)[(size_t)mg * Nc + ng] = v;
        else        ((__bf16*)C)[(size_t)mg * Nc + ng] = (__bf16)v;
      }
}

// ---------------- V transpose: (B*S, 512) -> key-group-major tiles ----------------
// Vt[((b*4+kvh)*32 + kt)*8192 + g*512 + d*4 + j] = V[b,s=kt*64+4g+j, kvh,d]
// (g in 0..15, d in 0..127, j in 0..3). PV 8B reads hit banks (2d)%32 -> min-pass.
__global__ __launch_bounds__(256) void transpose_v(const __bf16* __restrict__ V,
                                                   __bf16* __restrict__ Vt) {
  int bid = blockIdx.x;
  int dt = bid & 1, st = (bid >> 1) & 31, kvh = (bid >> 6) & 3, b = bid >> 8;
  __shared__ __align__(16) __bf16 tile[64][72];
  int t = threadIdx.x;
#pragma unroll
  for (int i = 0; i < 2; ++i) {
    int c = (i << 8) + t;
    int sr = c >> 3, cb = (c & 7) << 3;
    bf16x8 v = *(const bf16x8*)(V + (size_t)(b * S_LEN + st * 64 + sr) * 512 +
                                kvh * HDK + dt * 64 + cb);
    *(bf16x8*)(&tile[sr][cb]) = v;
  }
  __syncthreads();
  size_t tbase = ((size_t)(b * NKVH + kvh) * 32 + st) * 8192;
#pragma unroll
  for (int i = 0; i < 2; ++i) {
    int c = (i << 8) + t;
    int g = c & 15, dr0 = (c >> 4) << 1;  // 16 g-groups x 32 d-pairs
    bf16x8 o;
#pragma unroll
    for (int j = 0; j < 4; ++j) o[j] = tile[4 * g + j][dr0];
#pragma unroll
    for (int j = 0; j < 4; ++j) o[4 + j] = tile[4 * g + j][dr0 + 1];
    *(bf16x8*)(Vt + tbase + g * 512 + (size_t)(dt * 64 + dr0) * 4) = o;
  }
}

// ---------------- causal GQA flash attention, 32x32 swapped-QK^T ----------------
// 4 waves x 32 q-rows (QBLK=128), KVBLK=64, in-register softmax (lane owns q=lane&31).
// Zero-shuffle PV (pi = QK^T C/D key ownership); V in key-group-major LDS tiles so
// the two 8B B-fragment reads are bank-minimal; V staging is a pure linear copy.
__global__ __launch_bounds__(256, 2) void attn(const __bf16* __restrict__ Q,
                                               const __bf16* __restrict__ Kx,
                                               const __bf16* __restrict__ Vt,
                                               __bf16* __restrict__ Ctx) {
  int bid0 = blockIdx.x;
  int bid = ((bid0 & 7) << 6) | (bid0 >> 3);  // XCD swizzle: 512 blocks, 64/XCD
  int qt = 15 - (bid & 15);
  int h = (bid >> 4) & 15;
  int b = bid >> 8;
  int kvh = h >> 2;
  int q0 = qt << 7;
  int t = threadIdx.x, lane = t & 63, w = t >> 6;
  int qr = lane & 31;   // own q-row within wave
  int hi = lane >> 5;
  int qwb = q0 + (w << 5);

  __shared__ __align__(16) uint8_t Ks[2][16384];  // [64 key][128 d] bf16, swizzled
  __shared__ __align__(16) uint8_t Vs[2][16384];  // [16 g][128 d][4 key] bf16, linear

  const __bf16* kbase = Kx + (size_t)b * S_LEN * 512 + kvh * HDK;
  const __bf16* vbase = Vt + (size_t)(b * NKVH + kvh) * 32 * 8192;

  auto stage = [&](int kt, int bufi) {
#pragma unroll
    for (int i = 0; i < 4; ++i) {
      int c = (i << 8) + t;
      int krow = c >> 4;
      int kcolb = ((c & 15) << 4) ^ ((krow & 7) << 4);
      async16((const uint8_t*)(kbase + (size_t)((kt << 6) + krow) * 512) + kcolb,
              Ks[bufi] + c * 16);
      async16((const uint8_t*)(vbase + (size_t)kt * 8192) + c * 16,
              Vs[bufi] + c * 16);
    }
  };

  int NT = (qt << 1) + 2;
  stage(0, 0);

  // Q fragments: lane holds Q[q = qwb+qr][d = dk*16 + hi*8 + j]
  bf16x8 qf[8];
  {
    const __bf16* qrow = Q + (size_t)(b * S_LEN + qwb + qr) * DMODEL + h * HDK + hi * 8;
#pragma unroll
    for (int dk = 0; dk < 8; ++dk) qf[dk] = *(const bf16x8*)(qrow + dk * 16);
  }
  __syncthreads();  // stage(0) drained

  const float NEG = -3.0e38f;
  const float SC = 0.08838834764831845f;  // 1/sqrt(128)
  float m_run = NEG, l_run = 0.f;         // l_run: own-half partial until epilogue
  f32x16 acc[4] = {};  // O[q][d], 4 d-tiles of 32

  for (int kt = 0; kt < NT; ++kt) {
    int cur = kt & 1;
    if (kt + 1 < NT) stage(kt + 1, cur ^ 1);
    int k0 = kt << 6;
    if (k0 <= qwb + 31) {  // wave-uniform skip of fully-masked tiles
      const uint8_t* ks = Ks[cur];
      const uint8_t* vs = Vs[cur];

      // S^T = K Q^T : D[key][q], col=q=lane&31, row=(r&3)+8*(r>>2)+4*hi
      f32x16 st0 = {}, st1 = {};
      __builtin_amdgcn_s_setprio(1);
#pragma unroll
      for (int dk = 0; dk < 8; ++dk) {
        int cb = (dk << 5) + (hi << 4);
        int swz = (qr & 7) << 4;
        bf16x8 kf0 = *(const bf16x8*)(ks + qr * 256 + (cb ^ swz));
        st0 = mfma32(kf0, qf[dk], st0);
        bf16x8 kf1 = *(const bf16x8*)(ks + (32 + qr) * 256 + (cb ^ swz));
        st1 = mfma32(kf1, qf[dk], st1);
      }
      __builtin_amdgcn_s_setprio(0);

      // causal mask (diagonal-adjacent tiles only)
      if (k0 + 63 > qwb) {
#pragma unroll
        for (int r = 0; r < 16; ++r) {
          int kl = (r & 3) + ((r >> 2) << 3) + (hi << 2);
          st0[r] = (k0 + kl > qwb + qr) ? NEG : st0[r];
          st1[r] = (k0 + 32 + kl > qwb + qr) ? NEG : st1[r];
        }
      }

      // row max: explicit binary tree (depth 5) + one cross-half merge
      float tm[16];
#pragma unroll
      for (int r = 0; r < 16; ++r) tm[r] = fmaxf(st0[r], st1[r]);
#pragma unroll
      for (int s = 8; s > 0; s >>= 1)
#pragma unroll
        for (int r = 0; r < s; ++r) tm[r] = fmaxf(tm[r], tm[r + s]);
      float mx = fmaxf(tm[0], __shfl_xor(tm[0], 32, 64));

      // defer-max: rescale only when max grows by >8/SC in raw score units
      if (__any(mx > m_run + 90.52f)) {
        float mn = fmaxf(m_run, mx);
        float al = __expf((m_run - mn) * SC);
        l_run *= al;
        m_run = mn;
#pragma unroll
        for (int i = 0; i < 16; ++i) {
          float alr = __shfl(al, (i & 3) + ((i >> 2) << 3) + (hi << 2), 64);
          acc[0][i] *= alr; acc[1][i] *= alr; acc[2][i] *= alr; acc[3][i] *= alr;
        }
      }

      float mSC = m_run * SC;
      float p0[16], p1[16];
#pragma unroll
      for (int r = 0; r < 16; ++r) p0[r] = __expf(fmaf(st0[r], SC, -mSC));
#pragma unroll
      for (int r = 0; r < 16; ++r) p1[r] = __expf(fmaf(st1[r], SC, -mSC));
      // row sum: binary tree; cross-half merge deferred to epilogue (additive)
      float ts[16];
#pragma unroll
      for (int r = 0; r < 16; ++r) ts[r] = p0[r] + p1[r];
#pragma unroll
      for (int s = 8; s > 0; s >>= 1)
#pragma unroll
        for (int r = 0; r < s; ++r) ts[r] += ts[r + s];
      l_run += ts[0];

      // zero-shuffle A-fragments: pi(hi*8+j) = (j&3)+8*(j>>2)+4*hi matches the
      // QK^T C/D key ownership -> own p regs pack directly into pa[kc].
      bf16x8 pa[4];
      {
        union { bf16x8 v; uint32_t u[4]; } t0, t1, t2, t3;
#pragma unroll
        for (int i = 0; i < 4; ++i) {
          t0.u[i] = pkbf16(p0[2 * i], p0[2 * i + 1]);
          t1.u[i] = pkbf16(p0[8 + 2 * i], p0[9 + 2 * i]);
          t2.u[i] = pkbf16(p1[2 * i], p1[2 * i + 1]);
          t3.u[i] = pkbf16(p1[8 + 2 * i], p1[9 + 2 * i]);
        }
        pa[0] = t0.v; pa[1] = t1.v; pa[2] = t2.v; pa[3] = t3.v;
      }

      // O += P V : B-fragment = V keys {16kc+4hi..+3} (g0) and {16kc+8+4hi..+3} (g1)
      // at d-row; key-group-major layout makes both 8B reads bank-minimal.
      __builtin_amdgcn_s_setprio(1);
#pragma unroll
      for (int dt = 0; dt < 4; ++dt) {
        int row = (dt << 5) + qr;  // d index 0..127
#pragma unroll
        for (int kc = 0; kc < 4; ++kc) {
          int g0 = (kc << 2) + hi;
          union { bf16x8 v; uint64_t q[2]; } vfu;
          vfu.q[0] = *(const uint64_t*)(vs + (g0 << 10) + (row << 3));
          vfu.q[1] = *(const uint64_t*)(vs + ((g0 + 2) << 10) + (row << 3));
          acc[dt] = mfma32(pa[kc], vfu.v, acc[dt]);
        }
      }
      __builtin_amdgcn_s_setprio(0);
    }
    __syncthreads();  // single barrier: drains next-tile stage, releases cur buf
  }

  // epilogue: merge l halves once, normalize by per-row l, write out
  l_run += __shfl_xor(l_run, 32, 64);
#pragma unroll
  for (int i = 0; i < 16; ++i) {
    int rm = (i & 3) + ((i >> 2) << 3) + (hi << 2);
    float lr = __shfl(l_run, rm, 64);
    float inv = 1.0f / lr;
    size_t rowoff = (size_t)(b * S_LEN + qwb + rm) * DMODEL + h * HDK + qr;
#pragma unroll
    for (int dt = 0; dt < 4; ++dt)
      Ctx[rowoff + (dt << 5)] = (__bf16)(acc[dt][i] * inv);
  }
}

// ---------------- launch ----------------
extern "C" void kernel_launch(void* const* d_in, const int* in_sizes, int n_in,
                              void* d_out, int out_size, void* d_ws, size_t ws_size,
                              hipStream_t stream) {
  const float* x  = (const float*)d_in[0];
  const float* Wq = (const float*)d_in[1];
  const float* Wk = (const float*)d_in[2];
  const float* Wv = (const float*)d_in[3];
  const float* Wo = (const float*)d_in[4];
  float* out = (float*)d_out;

  const size_t MB = 1024 * 1024;
  uint8_t* ws = (uint8_t*)d_ws;
  __bf16* xb  = (__bf16*)(ws + 0 * MB);   // 16 MB  (4096 x 2048)
  __bf16* Wqb = (__bf16*)(ws + 16 * MB);  //  8 MB  (2048 x 2048)
  __bf16* Wkb = (__bf16*)(ws + 24 * MB);  //  2 MB  (512 x 2048)
  __bf16* Wvb = (__bf16*)(ws + 26 * MB);  //  2 MB
  __bf16* Wob = (__bf16*)(ws + 28 * MB);  //  8 MB
  __bf16* Qb  = (__bf16*)(ws + 36 * MB);  // 16 MB  (4096 x 2048)
  __bf16* Kb  = (__bf16*)(ws + 52 * MB);  //  4 MB  (4096 x 512)
  __bf16* Vb  = (__bf16*)(ws + 56 * MB);  //  4 MB
  __bf16* Vtb = (__bf16*)(ws + 60 * MB);  //  4 MB  (key-group-major tiles)
  __bf16* Ctx = (__bf16*)(ws + 64 * MB);  // 16 MB  (4096 x 2048)

  // fused conversion: 18.9M elems / 8 per thread / 256 per block = 9216 blocks
  cvt_all<<<9216, 256, 0, stream>>>(x, Wq, Wk, Wv, Wo, xb, Wqb, Wkb, Wvb, Wob);

  // fused QKV projection: (4096x2048) x [Wq;Wk;Wv]^T, N = 2048+512+512
  gemm_bt<false><<<(4096 / 128) * (3072 / 128), 256, 0, stream>>>(
      xb, Wqb, Wkb, Wvb, (void*)Qb, (void*)Kb, (void*)Vb, 3072, 2048, 2560, 2048);

  transpose_v<<<512, 256, 0, stream>>>(Vb, Vtb);

  attn<<<512, 256, 0, stream>>>(Qb, Kb, Vtb, Ctx);

  // output projection: (4096x2048) x (2048x2048)^T -> fp32
  gemm_bt<true><<<(4096 / 128) * (2048 / 128), 256, 0, stream>>>(
      Ctx, Wob, Wob, Wob, (void*)out, (void*)out, (void*)out, 2048, 2048, 2048, 2048);
}

// Round 12
// 193.866 us; speedup vs baseline: 1.6030x; 1.0012x over previous
//
#include <hip/hip_runtime.h>
#include <stdint.h>

#define S_LEN 2048
#define DMODEL 2048
#define NQH 16
#define NKVH 4
#define HDK 128

typedef __bf16 bf16x8 __attribute__((ext_vector_type(8)));
typedef float f32x4 __attribute__((ext_vector_type(4)));
typedef float f32x16 __attribute__((ext_vector_type(16)));

__device__ __forceinline__ void async16(const void* g, void* l) {
  __builtin_amdgcn_global_load_lds((const __attribute__((address_space(1))) void*)g,
                                   (__attribute__((address_space(3))) void*)l,
                                   16, 0, 0);
}

__device__ __forceinline__ f32x4 mfma16(bf16x8 a, bf16x8 b, f32x4 c) {
  return __builtin_amdgcn_mfma_f32_16x16x32_bf16(a, b, c, 0, 0, 0);
}
__device__ __forceinline__ f32x16 mfma32(bf16x8 a, bf16x8 b, f32x16 c) {
  return __builtin_amdgcn_mfma_f32_32x32x16_bf16(a, b, c, 0, 0, 0);
}
__device__ __forceinline__ uint32_t pkbf16(float lo, float hi) {
  uint32_t r;
  asm("v_cvt_pk_bf16_f32 %0, %1, %2" : "=v"(r) : "v"(lo), "v"(hi));
  return r;
}

// ---------------- fused fp32 -> bf16 conversion (all 5 tensors) ----------------
__global__ __launch_bounds__(256) void cvt_all(
    const float* __restrict__ i0, const float* __restrict__ i1,
    const float* __restrict__ i2, const float* __restrict__ i3,
    const float* __restrict__ i4, __bf16* __restrict__ o0,
    __bf16* __restrict__ o1, __bf16* __restrict__ o2, __bf16* __restrict__ o3,
    __bf16* __restrict__ o4) {
  int v = blockIdx.x * 256 + threadIdx.x;  // vec8 index; total 2359296
  const float* in;
  __bf16* out;
  int base;
  if (v < 1048576)      { in = i0; out = o0; base = 0; }
  else if (v < 1572864) { in = i1; out = o1; base = 1048576; }
  else if (v < 1703936) { in = i2; out = o2; base = 1572864; }
  else if (v < 1835008) { in = i3; out = o3; base = 1703936; }
  else                  { in = i4; out = o4; base = 1835008; }
  int i = (v - base) * 8;
  const float4* p = (const float4*)(in + i);
  float4 a = p[0], b = p[1];
  bf16x8 o;
  o[0] = (__bf16)a.x; o[1] = (__bf16)a.y; o[2] = (__bf16)a.z; o[3] = (__bf16)a.w;
  o[4] = (__bf16)b.x; o[5] = (__bf16)b.y; o[6] = (__bf16)b.z; o[7] = (__bf16)b.w;
  *(bf16x8*)(out + i) = o;
}

// ---------------- GEMM: C[m,n] = sum_k A[m,k]*B[n,k], 3-way N-routed ----------------
// VSEG2: the third segment's output is written in key-group-major Vt layout
// (fuses the former transpose_v kernel into the epilogue).
template <bool F32OUT, bool VSEG2>
__global__ __launch_bounds__(256) void gemm_bt(const __bf16* __restrict__ A,
                                               const __bf16* __restrict__ B0,
                                               const __bf16* __restrict__ B1,
                                               const __bf16* __restrict__ B2,
                                               void* __restrict__ C0,
                                               void* __restrict__ C1,
                                               void* __restrict__ C2,
                                               int Ntot, int Ns1, int Ns2, int K) {
  int nbn = Ntot >> 7;
  int nwg = gridDim.x;
  int bid = blockIdx.x;
  int bx = (bid & 7) * (nwg >> 3) + (bid >> 3);  // XCD swizzle (nwg % 8 == 0)
  int m0 = (bx / nbn) << 7;
  int n0g = (bx % nbn) << 7;
  const __bf16* B;
  void* C;
  int n0, Nc;
  bool seg2 = false;
  if (n0g < Ns1)      { B = B0; C = C0; n0 = n0g;       Nc = Ns1; }
  else if (n0g < Ns2) { B = B1; C = C1; n0 = n0g - Ns1; Nc = Ns2 - Ns1; }
  else                { B = B2; C = C2; n0 = n0g - Ns2; Nc = Ntot - Ns2; seg2 = true; }

  __shared__ __align__(16) uint8_t As[16384]; // [128][64] bf16, XOR-swizzled
  __shared__ __align__(16) uint8_t Bs[16384];

  int t = threadIdx.x, lane = t & 63, w = t >> 6;
  int wr = w >> 1, wc = w & 1;
  f32x4 acc[4][4] = {};

  for (int k0 = 0; k0 < K; k0 += 64) {
#pragma unroll
    for (int i = 0; i < 4; ++i) {
      int c = (i << 8) + t;
      int row = c >> 3;
      int colb = ((c & 7) << 4) ^ ((row & 7) << 4);
      async16((const uint8_t*)(A + (size_t)(m0 + row) * K + k0) + colb, As + c * 16);
      async16((const uint8_t*)(B + (size_t)(n0 + row) * K + k0) + colb, Bs + c * 16);
    }
    __syncthreads();
#pragma unroll
    for (int ks = 0; ks < 2; ++ks) {
      bf16x8 af[4], bfr[4];
#pragma unroll
      for (int m = 0; m < 4; ++m) {
        int row = wr * 64 + m * 16 + (lane & 15);
        int colb = ((ks << 6) + ((lane >> 4) << 4)) ^ ((row & 7) << 4);
        af[m] = *(const bf16x8*)(As + row * 128 + colb);
      }
#pragma unroll
      for (int n = 0; n < 4; ++n) {
        int row = wc * 64 + n * 16 + (lane & 15);
        int colb = ((ks << 6) + ((lane >> 4) << 4)) ^ ((row & 7) << 4);
        bfr[n] = *(const bf16x8*)(Bs + row * 128 + colb);
      }
      __builtin_amdgcn_s_setprio(1);
#pragma unroll
      for (int m = 0; m < 4; ++m)
#pragma unroll
        for (int n = 0; n < 4; ++n)
          acc[m][n] = mfma16(af[m], bfr[n], acc[m][n]);
      __builtin_amdgcn_s_setprio(0);
    }
    __syncthreads();
  }
#pragma unroll
  for (int m = 0; m < 4; ++m)
#pragma unroll
    for (int n = 0; n < 4; ++n)
#pragma unroll
      for (int j = 0; j < 4; ++j) {
        int mg = m0 + wr * 64 + m * 16 + ((lane >> 4) << 2) + j;
        int ng = n0 + wc * 64 + n * 16 + (lane & 15);
        float v = acc[m][n][j];
        if (VSEG2 && seg2) {
          // V output -> key-group-major Vt tiles:
          // Vt[((b*4+kvh)*32 + s/64)*8192 + ((s>>2)&15)*512 + d*4 + (s&3)]
          int bb = mg >> 11, s = mg & 2047;
          size_t vidx = ((size_t)((bb << 2) + (ng >> 7)) * 32 + (s >> 6)) * 8192 +
                        (size_t)((s >> 2) & 15) * 512 + (size_t)(ng & 127) * 4 +
                        (s & 3);
          ((__bf16*)C)[vidx] = (__bf16)v;
        } else if (F32OUT) {
          ((float*)C)[(size_t)mg * Nc + ng] = v;
        } else {
          ((__bf16*)C)[(size_t)mg * Nc + ng] = (__bf16)v;
        }
      }
}

// ---------------- causal GQA flash attention, 32x32 swapped-QK^T ----------------
// 4 waves x 32 q-rows (QBLK=128), KVBLK=64, in-register softmax (lane owns q=lane&31).
// Zero-shuffle PV (pi = QK^T C/D key ownership); V in key-group-major LDS tiles;
// QK^T split into 4 independent MFMA chains for intra-wave latency hiding.
__global__ __launch_bounds__(256, 2) void attn(const __bf16* __restrict__ Q,
                                               const __bf16* __restrict__ Kx,
                                               const __bf16* __restrict__ Vt,
                                               __bf16* __restrict__ Ctx) {
  int bid0 = blockIdx.x;
  int bid = ((bid0 & 7) << 6) | (bid0 >> 3);  // XCD swizzle: 512 blocks, 64/XCD
  int qt = 15 - (bid & 15);
  int h = (bid >> 4) & 15;
  int b = bid >> 8;
  int kvh = h >> 2;
  int q0 = qt << 7;
  int t = threadIdx.x, lane = t & 63, w = t >> 6;
  int qr = lane & 31;   // own q-row within wave
  int hi = lane >> 5;
  int qwb = q0 + (w << 5);

  __shared__ __align__(16) uint8_t Ks[2][16384];  // [64 key][128 d] bf16, swizzled
  __shared__ __align__(16) uint8_t Vs[2][16384];  // [16 g][128 d][4 key] bf16, linear

  const __bf16* kbase = Kx + (size_t)b * S_LEN * 512 + kvh * HDK;
  const __bf16* vbase = Vt + (size_t)(b * NKVH + kvh) * 32 * 8192;

  auto stage = [&](int kt, int bufi) {
#pragma unroll
    for (int i = 0; i < 4; ++i) {
      int c = (i << 8) + t;
      int krow = c >> 4;
      int kcolb = ((c & 15) << 4) ^ ((krow & 7) << 4);
      async16((const uint8_t*)(kbase + (size_t)((kt << 6) + krow) * 512) + kcolb,
              Ks[bufi] + c * 16);
      async16((const uint8_t*)(vbase + (size_t)kt * 8192) + c * 16,
              Vs[bufi] + c * 16);
    }
  };

  int NT = (qt << 1) + 2;
  stage(0, 0);

  // Q fragments: lane holds Q[q = qwb+qr][d = dk*16 + hi*8 + j]
  bf16x8 qf[8];
  {
    const __bf16* qrow = Q + (size_t)(b * S_LEN + qwb + qr) * DMODEL + h * HDK + hi * 8;
#pragma unroll
    for (int dk = 0; dk < 8; ++dk) qf[dk] = *(const bf16x8*)(qrow + dk * 16);
  }
  __syncthreads();  // stage(0) drained

  const float NEG = -3.0e38f;
  const float SC = 0.08838834764831845f;  // 1/sqrt(128)
  float m_run = NEG, l_run = 0.f;         // l_run: own-half partial until epilogue
  f32x16 acc[4] = {};  // O[q][d], 4 d-tiles of 32

  for (int kt = 0; kt < NT; ++kt) {
    int cur = kt & 1;
    if (kt + 1 < NT) stage(kt + 1, cur ^ 1);
    int k0 = kt << 6;
    if (k0 <= qwb + 31) {  // wave-uniform skip of fully-masked tiles
      const uint8_t* ks = Ks[cur];
      const uint8_t* vs = Vs[cur];

      // S^T = K Q^T : D[key][q], col=q=lane&31, row=(r&3)+8*(r>>2)+4*hi
      // 4 independent MFMA chains (st0/st1 split over dk halves) for ILP.
      f32x16 st0 = {}, st1 = {}, st0b = {}, st1b = {};
      int swz = (qr & 7) << 4;
      __builtin_amdgcn_s_setprio(1);
#pragma unroll
      for (int dk = 0; dk < 4; ++dk) {
        int cb0 = (dk << 5) + (hi << 4);
        int cb1 = ((dk + 4) << 5) + (hi << 4);
        bf16x8 a0 = *(const bf16x8*)(ks + qr * 256 + (cb0 ^ swz));
        bf16x8 a1 = *(const bf16x8*)(ks + (32 + qr) * 256 + (cb0 ^ swz));
        bf16x8 b0 = *(const bf16x8*)(ks + qr * 256 + (cb1 ^ swz));
        bf16x8 b1 = *(const bf16x8*)(ks + (32 + qr) * 256 + (cb1 ^ swz));
        st0 = mfma32(a0, qf[dk], st0);
        st1 = mfma32(a1, qf[dk], st1);
        st0b = mfma32(b0, qf[dk + 4], st0b);
        st1b = mfma32(b1, qf[dk + 4], st1b);
      }
      __builtin_amdgcn_s_setprio(0);
      st0 = st0 + st0b;
      st1 = st1 + st1b;

      // causal mask (diagonal-adjacent tiles only)
      if (k0 + 63 > qwb) {
#pragma unroll
        for (int r = 0; r < 16; ++r) {
          int kl = (r & 3) + ((r >> 2) << 3) + (hi << 2);
          st0[r] = (k0 + kl > qwb + qr) ? NEG : st0[r];
          st1[r] = (k0 + 32 + kl > qwb + qr) ? NEG : st1[r];
        }
      }

      // row max: explicit binary tree (depth 5) + one cross-half merge
      float tm[16];
#pragma unroll
      for (int r = 0; r < 16; ++r) tm[r] = fmaxf(st0[r], st1[r]);
#pragma unroll
      for (int s = 8; s > 0; s >>= 1)
#pragma unroll
        for (int r = 0; r < s; ++r) tm[r] = fmaxf(tm[r], tm[r + s]);
      float mx = fmaxf(tm[0], __shfl_xor(tm[0], 32, 64));

      // defer-max: rescale only when max grows by >8/SC in raw score units
      if (__any(mx > m_run + 90.52f)) {
        float mn = fmaxf(m_run, mx);
        float al = __expf((m_run - mn) * SC);
        l_run *= al;
        m_run = mn;
#pragma unroll
        for (int i = 0; i < 16; ++i) {
          float alr = __shfl(al, (i & 3) + ((i >> 2) << 3) + (hi << 2), 64);
          acc[0][i] *= alr; acc[1][i] *= alr; acc[2][i] *= alr; acc[3][i] *= alr;
        }
      }

      float mSC = m_run * SC;
      float p0[16], p1[16];
#pragma unroll
      for (int r = 0; r < 16; ++r) p0[r] = __expf(fmaf(st0[r], SC, -mSC));
#pragma unroll
      for (int r = 0; r < 16; ++r) p1[r] = __expf(fmaf(st1[r], SC, -mSC));
      // row sum: binary tree; cross-half merge deferred to epilogue (additive)
      float ts[16];
#pragma unroll
      for (int r = 0; r < 16; ++r) ts[r] = p0[r] + p1[r];
#pragma unroll
      for (int s = 8; s > 0; s >>= 1)
#pragma unroll
        for (int r = 0; r < s; ++r) ts[r] += ts[r + s];
      l_run += ts[0];

      // zero-shuffle A-fragments: pi(hi*8+j) = (j&3)+8*(j>>2)+4*hi matches the
      // QK^T C/D key ownership -> own p regs pack directly into pa[kc].
      bf16x8 pa[4];
      {
        union { bf16x8 v; uint32_t u[4]; } t0, t1, t2, t3;
#pragma unroll
        for (int i = 0; i < 4; ++i) {
          t0.u[i] = pkbf16(p0[2 * i], p0[2 * i + 1]);
          t1.u[i] = pkbf16(p0[8 + 2 * i], p0[9 + 2 * i]);
          t2.u[i] = pkbf16(p1[2 * i], p1[2 * i + 1]);
          t3.u[i] = pkbf16(p1[8 + 2 * i], p1[9 + 2 * i]);
        }
        pa[0] = t0.v; pa[1] = t1.v; pa[2] = t2.v; pa[3] = t3.v;
      }

      // O += P V : B-fragment = V keys {16kc+4hi..+3} (g0) and {16kc+8+4hi..+3} (g1)
      // at d-row; key-group-major layout makes both 8B reads bank-minimal.
      __builtin_amdgcn_s_setprio(1);
#pragma unroll
      for (int dt = 0; dt < 4; ++dt) {
        int row = (dt << 5) + qr;  // d index 0..127
#pragma unroll
        for (int kc = 0; kc < 4; ++kc) {
          int g0 = (kc << 2) + hi;
          union { bf16x8 v; uint64_t q[2]; } vfu;
          vfu.q[0] = *(const uint64_t*)(vs + (g0 << 10) + (row << 3));
          vfu.q[1] = *(const uint64_t*)(vs + ((g0 + 2) << 10) + (row << 3));
          acc[dt] = mfma32(pa[kc], vfu.v, acc[dt]);
        }
      }
      __builtin_amdgcn_s_setprio(0);
    }
    __syncthreads();  // single barrier: drains next-tile stage, releases cur buf
  }

  // epilogue: merge l halves once, normalize by per-row l, write out
  l_run += __shfl_xor(l_run, 32, 64);
#pragma unroll
  for (int i = 0; i < 16; ++i) {
    int rm = (i & 3) + ((i >> 2) << 3) + (hi << 2);
    float lr = __shfl(l_run, rm, 64);
    float inv = 1.0f / lr;
    size_t rowoff = (size_t)(b * S_LEN + qwb + rm) * DMODEL + h * HDK + qr;
#pragma unroll
    for (int dt = 0; dt < 4; ++dt)
      Ctx[rowoff + (dt << 5)] = (__bf16)(acc[dt][i] * inv);
  }
}

// ---------------- launch ----------------
extern "C" void kernel_launch(void* const* d_in, const int* in_sizes, int n_in,
                              void* d_out, int out_size, void* d_ws, size_t ws_size,
                              hipStream_t stream) {
  const float* x  = (const float*)d_in[0];
  const float* Wq = (const float*)d_in[1];
  const float* Wk = (const float*)d_in[2];
  const float* Wv = (const float*)d_in[3];
  const float* Wo = (const float*)d_in[4];
  float* out = (float*)d_out;

  const size_t MB = 1024 * 1024;
  uint8_t* ws = (uint8_t*)d_ws;
  __bf16* xb  = (__bf16*)(ws + 0 * MB);   // 16 MB  (4096 x 2048)
  __bf16* Wqb = (__bf16*)(ws + 16 * MB);  //  8 MB  (2048 x 2048)
  __bf16* Wkb = (__bf16*)(ws + 24 * MB);  //  2 MB  (512 x 2048)
  __bf16* Wvb = (__bf16*)(ws + 26 * MB);  //  2 MB
  __bf16* Wob = (__bf16*)(ws + 28 * MB);  //  8 MB
  __bf16* Qb  = (__bf16*)(ws + 36 * MB);  // 16 MB  (4096 x 2048)
  __bf16* Kb  = (__bf16*)(ws + 52 * MB);  //  4 MB  (4096 x 512)
  __bf16* Vtb = (__bf16*)(ws + 60 * MB);  //  4 MB  (key-group-major tiles)
  __bf16* Ctx = (__bf16*)(ws + 64 * MB);  // 16 MB  (4096 x 2048)

  // fused conversion: 18.9M elems / 8 per thread / 256 per block = 9216 blocks
  cvt_all<<<9216, 256, 0, stream>>>(x, Wq, Wk, Wv, Wo, xb, Wqb, Wkb, Wvb, Wob);

  // fused QKV projection: (4096x2048) x [Wq;Wk;Wv]^T, N = 2048+512+512.
  // V segment's epilogue writes key-group-major Vt directly (transpose fused).
  gemm_bt<false, true><<<(4096 / 128) * (3072 / 128), 256, 0, stream>>>(
      xb, Wqb, Wkb, Wvb, (void*)Qb, (void*)Kb, (void*)Vtb, 3072, 2048, 2560, 2048);

  attn<<<512, 256, 0, stream>>>(Qb, Kb, Vtb, Ctx);

  // output projection: (4096x2048) x (2048x2048)^T -> fp32
  gemm_bt<true, false><<<(4096 / 128) * (2048 / 128), 256, 0, stream>>>(
      Ctx, Wob, Wob, Wob, (void*)out, (void*)out, (void*)out, 2048, 2048, 2048, 2048);
}

// Round 13
// 191.520 us; speedup vs baseline: 1.6226x; 1.0122x over previous
//
#include <hip/hip_runtime.h>
#include <stdint.h>

#define S_LEN 2048
#define DMODEL 2048
#define NQH 16
#define NKVH 4
#define HDK 128

typedef __bf16 bf16x8 __attribute__((ext_vector_type(8)));
typedef float f32x4 __attribute__((ext_vector_type(4)));
typedef float f32x16 __attribute__((ext_vector_type(16)));

__device__ __forceinline__ void async16(const void* g, void* l) {
  __builtin_amdgcn_global_load_lds((const __attribute__((address_space(1))) void*)g,
                                   (__attribute__((address_space(3))) void*)l,
                                   16, 0, 0);
}

__device__ __forceinline__ f32x4 mfma16(bf16x8 a, bf16x8 b, f32x4 c) {
  return __builtin_amdgcn_mfma_f32_16x16x32_bf16(a, b, c, 0, 0, 0);
}
__device__ __forceinline__ f32x16 mfma32(bf16x8 a, bf16x8 b, f32x16 c) {
  return __builtin_amdgcn_mfma_f32_32x32x16_bf16(a, b, c, 0, 0, 0);
}
__device__ __forceinline__ uint32_t pkbf16(float lo, float hi) {
  uint32_t r;
  asm("v_cvt_pk_bf16_f32 %0, %1, %2" : "=v"(r) : "v"(lo), "v"(hi));
  return r;
}

// ---------------- fused fp32 -> bf16 conversion (all 5 tensors) ----------------
__global__ __launch_bounds__(256) void cvt_all(
    const float* __restrict__ i0, const float* __restrict__ i1,
    const float* __restrict__ i2, const float* __restrict__ i3,
    const float* __restrict__ i4, __bf16* __restrict__ o0,
    __bf16* __restrict__ o1, __bf16* __restrict__ o2, __bf16* __restrict__ o3,
    __bf16* __restrict__ o4) {
  int v = blockIdx.x * 256 + threadIdx.x;  // vec8 index; total 2359296
  const float* in;
  __bf16* out;
  int base;
  if (v < 1048576)      { in = i0; out = o0; base = 0; }
  else if (v < 1572864) { in = i1; out = o1; base = 1048576; }
  else if (v < 1703936) { in = i2; out = o2; base = 1572864; }
  else if (v < 1835008) { in = i3; out = o3; base = 1703936; }
  else                  { in = i4; out = o4; base = 1835008; }
  int i = (v - base) * 8;
  const float4* p = (const float4*)(in + i);
  float4 a = p[0], b = p[1];
  bf16x8 o;
  o[0] = (__bf16)a.x; o[1] = (__bf16)a.y; o[2] = (__bf16)a.z; o[3] = (__bf16)a.w;
  o[4] = (__bf16)b.x; o[5] = (__bf16)b.y; o[6] = (__bf16)b.z; o[7] = (__bf16)b.w;
  *(bf16x8*)(out + i) = o;
}

// ---------------- GEMM: C[m,n] = sum_k A[m,k]*B[n,k], 3-way N-routed ----------------
// VSEG2: the third segment's output is written in key-group-major Vt layout
// (fuses the former transpose_v kernel into the epilogue).
template <bool F32OUT, bool VSEG2>
__global__ __launch_bounds__(256) void gemm_bt(const __bf16* __restrict__ A,
                                               const __bf16* __restrict__ B0,
                                               const __bf16* __restrict__ B1,
                                               const __bf16* __restrict__ B2,
                                               void* __restrict__ C0,
                                               void* __restrict__ C1,
                                               void* __restrict__ C2,
                                               int Ntot, int Ns1, int Ns2, int K) {
  int nbn = Ntot >> 7;
  int nwg = gridDim.x;
  int bid = blockIdx.x;
  int bx = (bid & 7) * (nwg >> 3) + (bid >> 3);  // XCD swizzle (nwg % 8 == 0)
  int m0 = (bx / nbn) << 7;
  int n0g = (bx % nbn) << 7;
  const __bf16* B;
  void* C;
  int n0, Nc;
  bool seg2 = false;
  if (n0g < Ns1)      { B = B0; C = C0; n0 = n0g;       Nc = Ns1; }
  else if (n0g < Ns2) { B = B1; C = C1; n0 = n0g - Ns1; Nc = Ns2 - Ns1; }
  else                { B = B2; C = C2; n0 = n0g - Ns2; Nc = Ntot - Ns2; seg2 = true; }

  __shared__ __align__(16) uint8_t As[16384]; // [128][64] bf16, XOR-swizzled
  __shared__ __align__(16) uint8_t Bs[16384];

  int t = threadIdx.x, lane = t & 63, w = t >> 6;
  int wr = w >> 1, wc = w & 1;
  f32x4 acc[4][4] = {};

  for (int k0 = 0; k0 < K; k0 += 64) {
#pragma unroll
    for (int i = 0; i < 4; ++i) {
      int c = (i << 8) + t;
      int row = c >> 3;
      int colb = ((c & 7) << 4) ^ ((row & 7) << 4);
      async16((const uint8_t*)(A + (size_t)(m0 + row) * K + k0) + colb, As + c * 16);
      async16((const uint8_t*)(B + (size_t)(n0 + row) * K + k0) + colb, Bs + c * 16);
    }
    __syncthreads();
#pragma unroll
    for (int ks = 0; ks < 2; ++ks) {
      bf16x8 af[4], bfr[4];
#pragma unroll
      for (int m = 0; m < 4; ++m) {
        int row = wr * 64 + m * 16 + (lane & 15);
        int colb = ((ks << 6) + ((lane >> 4) << 4)) ^ ((row & 7) << 4);
        af[m] = *(const bf16x8*)(As + row * 128 + colb);
      }
#pragma unroll
      for (int n = 0; n < 4; ++n) {
        int row = wc * 64 + n * 16 + (lane & 15);
        int colb = ((ks << 6) + ((lane >> 4) << 4)) ^ ((row & 7) << 4);
        bfr[n] = *(const bf16x8*)(Bs + row * 128 + colb);
      }
      __builtin_amdgcn_s_setprio(1);
#pragma unroll
      for (int m = 0; m < 4; ++m)
#pragma unroll
        for (int n = 0; n < 4; ++n)
          acc[m][n] = mfma16(af[m], bfr[n], acc[m][n]);
      __builtin_amdgcn_s_setprio(0);
    }
    __syncthreads();
  }
#pragma unroll
  for (int m = 0; m < 4; ++m)
#pragma unroll
    for (int n = 0; n < 4; ++n)
#pragma unroll
      for (int j = 0; j < 4; ++j) {
        int mg = m0 + wr * 64 + m * 16 + ((lane >> 4) << 2) + j;
        int ng = n0 + wc * 64 + n * 16 + (lane & 15);
        float v = acc[m][n][j];
        if (VSEG2 && seg2) {
          // V output -> key-group-major Vt tiles:
          // Vt[((b*4+kvh)*32 + s/64)*8192 + ((s>>2)&15)*512 + d*4 + (s&3)]
          int bb = mg >> 11, s = mg & 2047;
          size_t vidx = ((size_t)((bb << 2) + (ng >> 7)) * 32 + (s >> 6)) * 8192 +
                        (size_t)((s >> 2) & 15) * 512 + (size_t)(ng & 127) * 4 +
                        (s & 3);
          ((__bf16*)C)[vidx] = (__bf16)v;
        } else if (F32OUT) {
          ((float*)C)[(size_t)mg * Nc + ng] = v;
        } else {
          ((__bf16*)C)[(size_t)mg * Nc + ng] = (__bf16)v;
        }
      }
}

// ---------------- causal GQA flash attention, 32x32 swapped-QK^T ----------------
// 4 waves x 32 q-rows (QBLK=128), KVBLK=64, in-register softmax (lane owns q=lane&31).
// Zero-shuffle PV (pi = QK^T C/D key ownership); V in key-group-major LDS tiles so
// the two 8B B-fragment reads are bank-minimal; V staging is a pure linear copy.
__global__ __launch_bounds__(256, 2) void attn(const __bf16* __restrict__ Q,
                                               const __bf16* __restrict__ Kx,
                                               const __bf16* __restrict__ Vt,
                                               __bf16* __restrict__ Ctx) {
  int bid0 = blockIdx.x;
  int bid = ((bid0 & 7) << 6) | (bid0 >> 3);  // XCD swizzle: 512 blocks, 64/XCD
  int qt = 15 - (bid & 15);
  int h = (bid >> 4) & 15;
  int b = bid >> 8;
  int kvh = h >> 2;
  int q0 = qt << 7;
  int t = threadIdx.x, lane = t & 63, w = t >> 6;
  int qr = lane & 31;   // own q-row within wave
  int hi = lane >> 5;
  int qwb = q0 + (w << 5);

  __shared__ __align__(16) uint8_t Ks[2][16384];  // [64 key][128 d] bf16, swizzled
  __shared__ __align__(16) uint8_t Vs[2][16384];  // [16 g][128 d][4 key] bf16, linear

  const __bf16* kbase = Kx + (size_t)b * S_LEN * 512 + kvh * HDK;
  const __bf16* vbase = Vt + (size_t)(b * NKVH + kvh) * 32 * 8192;

  auto stage = [&](int kt, int bufi) {
#pragma unroll
    for (int i = 0; i < 4; ++i) {
      int c = (i << 8) + t;
      int krow = c >> 4;
      int kcolb = ((c & 15) << 4) ^ ((krow & 7) << 4);
      async16((const uint8_t*)(kbase + (size_t)((kt << 6) + krow) * 512) + kcolb,
              Ks[bufi] + c * 16);
      async16((const uint8_t*)(vbase + (size_t)kt * 8192) + c * 16,
              Vs[bufi] + c * 16);
    }
  };

  int NT = (qt << 1) + 2;
  stage(0, 0);

  // Q fragments: lane holds Q[q = qwb+qr][d = dk*16 + hi*8 + j]
  bf16x8 qf[8];
  {
    const __bf16* qrow = Q + (size_t)(b * S_LEN + qwb + qr) * DMODEL + h * HDK + hi * 8;
#pragma unroll
    for (int dk = 0; dk < 8; ++dk) qf[dk] = *(const bf16x8*)(qrow + dk * 16);
  }
  __syncthreads();  // stage(0) drained

  const float NEG = -3.0e38f;
  const float SC = 0.08838834764831845f;  // 1/sqrt(128)
  float m_run = NEG, l_run = 0.f;         // l_run: own-half partial until epilogue
  f32x16 acc[4] = {};  // O[q][d], 4 d-tiles of 32

  for (int kt = 0; kt < NT; ++kt) {
    int cur = kt & 1;
    if (kt + 1 < NT) stage(kt + 1, cur ^ 1);
    int k0 = kt << 6;
    if (k0 <= qwb + 31) {  // wave-uniform skip of fully-masked tiles
      const uint8_t* ks = Ks[cur];
      const uint8_t* vs = Vs[cur];

      // S^T = K Q^T : D[key][q], col=q=lane&31, row=(r&3)+8*(r>>2)+4*hi
      f32x16 st0 = {}, st1 = {};
      __builtin_amdgcn_s_setprio(1);
#pragma unroll
      for (int dk = 0; dk < 8; ++dk) {
        int cb = (dk << 5) + (hi << 4);
        int swz = (qr & 7) << 4;
        bf16x8 kf0 = *(const bf16x8*)(ks + qr * 256 + (cb ^ swz));
        st0 = mfma32(kf0, qf[dk], st0);
        bf16x8 kf1 = *(const bf16x8*)(ks + (32 + qr) * 256 + (cb ^ swz));
        st1 = mfma32(kf1, qf[dk], st1);
      }
      __builtin_amdgcn_s_setprio(0);

      // causal mask (diagonal-adjacent tiles only)
      if (k0 + 63 > qwb) {
#pragma unroll
        for (int r = 0; r < 16; ++r) {
          int kl = (r & 3) + ((r >> 2) << 3) + (hi << 2);
          st0[r] = (k0 + kl > qwb + qr) ? NEG : st0[r];
          st1[r] = (k0 + 32 + kl > qwb + qr) ? NEG : st1[r];
        }
      }

      // row max: explicit binary tree (depth 5) + one cross-half merge
      float tm[16];
#pragma unroll
      for (int r = 0; r < 16; ++r) tm[r] = fmaxf(st0[r], st1[r]);
#pragma unroll
      for (int s = 8; s > 0; s >>= 1)
#pragma unroll
        for (int r = 0; r < s; ++r) tm[r] = fmaxf(tm[r], tm[r + s]);
      float mx = fmaxf(tm[0], __shfl_xor(tm[0], 32, 64));

      // defer-max: rescale only when max grows by >8/SC in raw score units
      if (__any(mx > m_run + 90.52f)) {
        float mn = fmaxf(m_run, mx);
        float al = __expf((m_run - mn) * SC);
        l_run *= al;
        m_run = mn;
#pragma unroll
        for (int i = 0; i < 16; ++i) {
          float alr = __shfl(al, (i & 3) + ((i >> 2) << 3) + (hi << 2), 64);
          acc[0][i] *= alr; acc[1][i] *= alr; acc[2][i] *= alr; acc[3][i] *= alr;
        }
      }

      float mSC = m_run * SC;
      float p0[16], p1[16];
#pragma unroll
      for (int r = 0; r < 16; ++r) p0[r] = __expf(fmaf(st0[r], SC, -mSC));
#pragma unroll
      for (int r = 0; r < 16; ++r) p1[r] = __expf(fmaf(st1[r], SC, -mSC));
      // row sum: binary tree; cross-half merge deferred to epilogue (additive)
      float ts[16];
#pragma unroll
      for (int r = 0; r < 16; ++r) ts[r] = p0[r] + p1[r];
#pragma unroll
      for (int s = 8; s > 0; s >>= 1)
#pragma unroll
        for (int r = 0; r < s; ++r) ts[r] += ts[r + s];
      l_run += ts[0];

      // zero-shuffle A-fragments: pi(hi*8+j) = (j&3)+8*(j>>2)+4*hi matches the
      // QK^T C/D key ownership -> own p regs pack directly into pa[kc].
      bf16x8 pa[4];
      {
        union { bf16x8 v; uint32_t u[4]; } t0, t1, t2, t3;
#pragma unroll
        for (int i = 0; i < 4; ++i) {
          t0.u[i] = pkbf16(p0[2 * i], p0[2 * i + 1]);
          t1.u[i] = pkbf16(p0[8 + 2 * i], p0[9 + 2 * i]);
          t2.u[i] = pkbf16(p1[2 * i], p1[2 * i + 1]);
          t3.u[i] = pkbf16(p1[8 + 2 * i], p1[9 + 2 * i]);
        }
        pa[0] = t0.v; pa[1] = t1.v; pa[2] = t2.v; pa[3] = t3.v;
      }

      // O += P V : B-fragment = V keys {16kc+4hi..+3} (g0) and {16kc+8+4hi..+3} (g1)
      // at d-row; key-group-major layout makes both 8B reads bank-minimal.
      __builtin_amdgcn_s_setprio(1);
#pragma unroll
      for (int dt = 0; dt < 4; ++dt) {
        int row = (dt << 5) + qr;  // d index 0..127
#pragma unroll
        for (int kc = 0; kc < 4; ++kc) {
          int g0 = (kc << 2) + hi;
          union { bf16x8 v; uint64_t q[2]; } vfu;
          vfu.q[0] = *(const uint64_t*)(vs + (g0 << 10) + (row << 3));
          vfu.q[1] = *(const uint64_t*)(vs + ((g0 + 2) << 10) + (row << 3));
          acc[dt] = mfma32(pa[kc], vfu.v, acc[dt]);
        }
      }
      __builtin_amdgcn_s_setprio(0);
    }
    __syncthreads();  // single barrier: drains next-tile stage, releases cur buf
  }

  // epilogue: merge l halves once, normalize by per-row l, write out
  l_run += __shfl_xor(l_run, 32, 64);
#pragma unroll
  for (int i = 0; i < 16; ++i) {
    int rm = (i & 3) + ((i >> 2) << 3) + (hi << 2);
    float lr = __shfl(l_run, rm, 64);
    float inv = 1.0f / lr;
    size_t rowoff = (size_t)(b * S_LEN + qwb + rm) * DMODEL + h * HDK + qr;
#pragma unroll
    for (int dt = 0; dt < 4; ++dt)
      Ctx[rowoff + (dt << 5)] = (__bf16)(acc[dt][i] * inv);
  }
}

// ---------------- launch ----------------
extern "C" void kernel_launch(void* const* d_in, const int* in_sizes, int n_in,
                              void* d_out, int out_size, void* d_ws, size_t ws_size,
                              hipStream_t stream) {
  const float* x  = (const float*)d_in[0];
  const float* Wq = (const float*)d_in[1];
  const float* Wk = (const float*)d_in[2];
  const float* Wv = (const float*)d_in[3];
  const float* Wo = (const float*)d_in[4];
  float* out = (float*)d_out;

  const size_t MB = 1024 * 1024;
  uint8_t* ws = (uint8_t*)d_ws;
  __bf16* xb  = (__bf16*)(ws + 0 * MB);   // 16 MB  (4096 x 2048)
  __bf16* Wqb = (__bf16*)(ws + 16 * MB);  //  8 MB  (2048 x 2048)
  __bf16* Wkb = (__bf16*)(ws + 24 * MB);  //  2 MB  (512 x 2048)
  __bf16* Wvb = (__bf16*)(ws + 26 * MB);  //  2 MB
  __bf16* Wob = (__bf16*)(ws + 28 * MB);  //  8 MB
  __bf16* Qb  = (__bf16*)(ws + 36 * MB);  // 16 MB  (4096 x 2048)
  __bf16* Kb  = (__bf16*)(ws + 52 * MB);  //  4 MB  (4096 x 512)
  __bf16* Vtb = (__bf16*)(ws + 60 * MB);  //  4 MB  (key-group-major tiles)
  __bf16* Ctx = (__bf16*)(ws + 64 * MB);  // 16 MB  (4096 x 2048)

  // fused conversion: 18.9M elems / 8 per thread / 256 per block = 9216 blocks
  cvt_all<<<9216, 256, 0, stream>>>(x, Wq, Wk, Wv, Wo, xb, Wqb, Wkb, Wvb, Wob);

  // fused QKV projection: (4096x2048) x [Wq;Wk;Wv]^T, N = 2048+512+512.
  // V segment's epilogue writes key-group-major Vt directly (transpose fused).
  gemm_bt<false, true><<<(4096 / 128) * (3072 / 128), 256, 0, stream>>>(
      xb, Wqb, Wkb, Wvb, (void*)Qb, (void*)Kb, (void*)Vtb, 3072, 2048, 2560, 2048);

  attn<<<512, 256, 0, stream>>>(Qb, Kb, Vtb, Ctx);

  // output projection: (4096x2048) x (2048x2048)^T -> fp32
  gemm_bt<true, false><<<(4096 / 128) * (2048 / 128), 256, 0, stream>>>(
      Ctx, Wob, Wob, Wob, (void*)out, (void*)out, (void*)out, 2048, 2048, 2048, 2048);
}